// Round 1
// baseline (230.973 us; speedup 1.0000x reference)
//
#include <hip/hip_runtime.h>
#include <hip/hip_bf16.h>
#include <math.h>

#define B_ 4
#define T_ 512
#define D_ 768
#define H_ 12
#define FF_ 3072
#define DK_ 64
#define NTOK (B_*T_)
#define NEGV -1e9f

typedef unsigned short u16;
typedef __bf16 bfx8 __attribute__((ext_vector_type(8)));
typedef float f32x4 __attribute__((ext_vector_type(4)));
typedef u16 u16x8 __attribute__((ext_vector_type(8)));

__device__ __forceinline__ u16 f2bf(float f) {
  union { float f; unsigned u; } v; v.f = f;
  unsigned r = (v.u + 0x7FFFu + ((v.u >> 16) & 1u)) >> 16;   // RNE
  return (u16)r;
}

// ---------------- weight transpose + cast:  in (K,N) f32  ->  out (N,K) bf16
__global__ void transpose_cast(const float* __restrict__ in, u16* __restrict__ out, int K, int N)
{
  __shared__ float tile[32][33];
  int n0 = blockIdx.x * 32, k0 = blockIdx.y * 32;
  int tx = threadIdx.x, ty = threadIdx.y;   // (32,8)
  #pragma unroll
  for (int i = 0; i < 4; ++i) {
    int r = ty + i * 8;
    tile[r][tx] = in[(size_t)(k0 + r) * N + n0 + tx];
  }
  __syncthreads();
  #pragma unroll
  for (int i = 0; i < 4; ++i) {
    int r = ty + i * 8;
    out[(size_t)(n0 + r) * K + k0 + tx] = f2bf(tile[tx][r]);
  }
}

// ---------------- LayerNorm (row = 768) -> bf16
__global__ __launch_bounds__(256) void ln_cast(const float* __restrict__ x, const float* __restrict__ g,
                                               const float* __restrict__ b, u16* __restrict__ out)
{
  const int row = blockIdx.x;
  const int tid = threadIdx.x;
  const float* xr = x + (size_t)row * D_;
  float v0 = xr[tid], v1 = xr[tid + 256], v2 = xr[tid + 512];
  float s = v0 + v1 + v2;
  float sq = v0 * v0 + v1 * v1 + v2 * v2;
  #pragma unroll
  for (int o = 32; o > 0; o >>= 1) { s += __shfl_down(s, o); sq += __shfl_down(sq, o); }
  __shared__ float ss[4], s2[4];
  int w = tid >> 6;
  if ((tid & 63) == 0) { ss[w] = s; s2[w] = sq; }
  __syncthreads();
  s = ss[0] + ss[1] + ss[2] + ss[3];
  sq = s2[0] + s2[1] + s2[2] + s2[3];
  float mean = s * (1.0f / 768.0f);
  float inv = rsqrtf(sq * (1.0f / 768.0f) - mean * mean + 1e-5f);
  u16* orow = out + (size_t)row * D_;
  orow[tid]       = f2bf((v0 - mean) * inv * g[tid]       + b[tid]);
  orow[tid + 256] = f2bf((v1 - mean) * inv * g[tid + 256] + b[tid + 256]);
  orow[tid + 512] = f2bf((v2 - mean) * inv * g[tid + 512] + b[tid + 512]);
}

// ---------------- temporal bias MLP (+ padding mask), per (b,i,j), fp32
__global__ __launch_bounds__(256) void bias_mlp(const float* __restrict__ tmat, const int* __restrict__ pad,
    const float* __restrict__ w1, const float* __restrict__ b1,
    const float* __restrict__ w2, const float* __restrict__ b2,
    float* __restrict__ biasM)
{
  __shared__ float sw1[64], sb1[64], sw2[64];
  if (threadIdx.x < 64) {
    sw1[threadIdx.x] = w1[threadIdx.x];
    sb1[threadIdx.x] = b1[threadIdx.x];
    sw2[threadIdx.x] = w2[threadIdx.x];
  }
  __syncthreads();
  size_t idx = (size_t)blockIdx.x * 256 + threadIdx.x;   // over B*T*T
  float tm = 1.0f / logf(2.718281828459045f + tmat[idx]);
  float acc = b2[0];
  #pragma unroll
  for (int t = 0; t < 64; ++t) {
    float u = fmaf(tm, sw1[t], sb1[t]);
    u = u > 0.0f ? u : 0.2f * u;          // leaky_relu(0.2)
    acc = fmaf(u, sw2[t], acc);
  }
  biasM[idx] = (pad[idx] == 0) ? NEGV : acc;   // (B,1,T,T): same flat index
}

// ---------------- GEMM mainloop: C(M,N) = A(M,K) * BT(N,K)^T, 128x128 tile, BK=32
__device__ __forceinline__ void gemm_tile(const u16* __restrict__ A, const u16* __restrict__ BT,
                                          int K, int m0, int n0,
                                          u16 (*As)[40], u16 (*Bs)[40], f32x4 acc[4][4])
{
  const int tid = threadIdx.x;
  const int w = tid >> 6, lane = tid & 63;
  const int lr = lane & 15, lk = (lane >> 4) * 8;
  const int wm = (w >> 1) * 64, wn = (w & 1) * 64;
  for (int kt = 0; kt < K; kt += 32) {
    #pragma unroll
    for (int i = 0; i < 2; ++i) {
      int c = tid + i * 256;            // 512 chunks of 16B per matrix
      int row = c >> 2, off = (c & 3) * 8;
      *(u16x8*)&As[row][off] = *(const u16x8*)(A  + (size_t)(m0 + row) * K + kt + off);
      *(u16x8*)&Bs[row][off] = *(const u16x8*)(BT + (size_t)(n0 + row) * K + kt + off);
    }
    __syncthreads();
    bfx8 af[4], bfr[4];
    #pragma unroll
    for (int t = 0; t < 4; ++t) {
      af[t]  = *(const bfx8*)&As[wm + t * 16 + lr][lk];
      bfr[t] = *(const bfx8*)&Bs[wn + t * 16 + lr][lk];
    }
    #pragma unroll
    for (int rt = 0; rt < 4; ++rt)
      #pragma unroll
      for (int ct = 0; ct < 4; ++ct)
        acc[rt][ct] = __builtin_amdgcn_mfma_f32_16x16x32_bf16(af[rt], bfr[ct], acc[rt][ct], 0, 0, 0);
    __syncthreads();
  }
}

// EPI: 0 = (B,H,T,DK) bf16 with scale (q/k)   1 = (B,H,DK,T) bf16 (v)
//      2 = f32 + bias + resid                 3 = gelu -> bf16 row-major
template<int EPI>
__global__ __launch_bounds__(256) void gemm_bt(
    const u16* __restrict__ A, const u16* __restrict__ BT,
    const float* __restrict__ bias, const float* __restrict__ resid,
    void* __restrict__ outp, int M, int N, int K, float scale)
{
  __shared__ u16 As[128][40];
  __shared__ u16 Bs[128][40];
  const int m0 = blockIdx.y * 128, n0 = blockIdx.x * 128;
  f32x4 acc[4][4];
  #pragma unroll
  for (int a = 0; a < 4; ++a)
    #pragma unroll
    for (int bb = 0; bb < 4; ++bb) acc[a][bb] = (f32x4){0.f, 0.f, 0.f, 0.f};
  gemm_tile(A, BT, K, m0, n0, As, Bs, acc);
  const int tid = threadIdx.x;
  const int w = tid >> 6, lane = tid & 63;
  const int lr = lane & 15;
  const int wm = (w >> 1) * 64, wn = (w & 1) * 64;
  #pragma unroll
  for (int rt = 0; rt < 4; ++rt)
    #pragma unroll
    for (int ct = 0; ct < 4; ++ct)
      #pragma unroll
      for (int r = 0; r < 4; ++r) {
        int m = m0 + wm + rt * 16 + (lane >> 4) * 4 + r;
        int n = n0 + wn + ct * 16 + lr;
        float val = acc[rt][ct][r] + bias[n];
        if (EPI == 0) {
          val *= scale;
          int b = m >> 9, t = m & 511, hh = n >> 6, d = n & 63;
          ((u16*)outp)[(((size_t)b * H_ + hh) * T_ + t) * DK_ + d] = f2bf(val);
        } else if (EPI == 1) {
          int b = m >> 9, t = m & 511, hh = n >> 6, d = n & 63;
          ((u16*)outp)[(((size_t)b * H_ + hh) * DK_ + d) * T_ + t] = f2bf(val);
        } else if (EPI == 2) {
          ((float*)outp)[(size_t)m * N + n] = val + resid[(size_t)m * N + n];
        } else {
          float gl = 0.5f * val * (1.0f + erff(val * 0.7071067811865475f));
          ((u16*)outp)[(size_t)m * N + n] = f2bf(gl);
        }
      }
}

// QKV fused over blockIdx.z (0=q,1=k,2=v) for grid parallelism (288 blocks)
__global__ __launch_bounds__(256) void gemm_qkv(
    const u16* __restrict__ A,
    const u16* __restrict__ wqT, const u16* __restrict__ wkT, const u16* __restrict__ wvT,
    const float* __restrict__ bq, const float* __restrict__ bk, const float* __restrict__ bv,
    u16* __restrict__ qo, u16* __restrict__ ko, u16* __restrict__ vo)
{
  __shared__ u16 As[128][40];
  __shared__ u16 Bs[128][40];
  const int z = blockIdx.z;
  const u16* BT = z == 0 ? wqT : (z == 1 ? wkT : wvT);
  const float* bias = z == 0 ? bq : (z == 1 ? bk : bv);
  u16* outp = z == 0 ? qo : (z == 1 ? ko : vo);
  const float scale = z == 0 ? 0.125f : 1.0f;   // DK^-0.5 folded into q
  const int m0 = blockIdx.y * 128, n0 = blockIdx.x * 128;
  f32x4 acc[4][4];
  #pragma unroll
  for (int a = 0; a < 4; ++a)
    #pragma unroll
    for (int bb = 0; bb < 4; ++bb) acc[a][bb] = (f32x4){0.f, 0.f, 0.f, 0.f};
  gemm_tile(A, BT, D_, m0, n0, As, Bs, acc);
  const int tid = threadIdx.x;
  const int w = tid >> 6, lane = tid & 63;
  const int lr = lane & 15;
  const int wm = (w >> 1) * 64, wn = (w & 1) * 64;
  #pragma unroll
  for (int rt = 0; rt < 4; ++rt)
    #pragma unroll
    for (int ct = 0; ct < 4; ++ct)
      #pragma unroll
      for (int r = 0; r < 4; ++r) {
        int m = m0 + wm + rt * 16 + (lane >> 4) * 4 + r;
        int n = n0 + wn + ct * 16 + lr;
        float val = (acc[rt][ct][r] + bias[n]) * scale;
        int b = m >> 9, t = m & 511, hh = n >> 6, d = n & 63;
        if (z < 2) outp[(((size_t)b * H_ + hh) * T_ + t) * DK_ + d] = f2bf(val);
        else       outp[(((size_t)b * H_ + hh) * DK_ + d) * T_ + t] = f2bf(val);
      }
}

// ---------------- attention: block = (b,h) x 16 q-rows; S strip in LDS
__global__ __launch_bounds__(256) void attn_kernel(
    const u16* __restrict__ q, const u16* __restrict__ k, const u16* __restrict__ vT,
    const float* __restrict__ biasM, u16* __restrict__ ao)
{
  __shared__ float S[16 * 516];          // 16 rows x 512 cols, +4 pad (2-way banks)
  __shared__ float rowinv[16];
  const int tid = threadIdx.x;
  const int w = tid >> 6, lane = tid & 63;
  const int lr = lane & 15, lk = (lane >> 4) * 8;
  const int bh = blockIdx.y;             // b*H + h
  const int b = bh / H_, h = bh % H_;
  const int i0 = blockIdx.x * 16;

  // phase 1: S = (q*scale) k^T + bias, causal-masked
  bfx8 qf[2];
  #pragma unroll
  for (int ks = 0; ks < 2; ++ks)
    qf[ks] = *(const bfx8*)(q + ((size_t)bh * T_ + i0 + lr) * DK_ + ks * 32 + lk);
  const int jbase = w * 128;
  #pragma unroll
  for (int ct = 0; ct < 8; ++ct) {
    int j0 = jbase + ct * 16;
    bfx8 kf0 = *(const bfx8*)(k + ((size_t)bh * T_ + j0 + lr) * DK_ + lk);
    bfx8 kf1 = *(const bfx8*)(k + ((size_t)bh * T_ + j0 + lr) * DK_ + 32 + lk);
    f32x4 acc = (f32x4){0.f, 0.f, 0.f, 0.f};
    acc = __builtin_amdgcn_mfma_f32_16x16x32_bf16(qf[0], kf0, acc, 0, 0, 0);
    acc = __builtin_amdgcn_mfma_f32_16x16x32_bf16(qf[1], kf1, acc, 0, 0, 0);
    int j = j0 + lr;
    #pragma unroll
    for (int r = 0; r < 4; ++r) {
      int il = (lane >> 4) * 4 + r;
      int i = i0 + il;
      float s = acc[r] + biasM[((size_t)b * T_ + i) * T_ + j];
      if (j > i && i != 0) s = NEGV;     // causal, CLS row 0 fully visible
      S[il * 516 + j0 + lr] = s;
    }
  }
  __syncthreads();

  // phase 2: row softmax (16 lanes per row, 32 cols each)
  {
    int row = tid >> 4;
    int c0 = (tid & 15) * 32;
    float m = -3.4e38f;
    #pragma unroll
    for (int i2 = 0; i2 < 8; ++i2) {
      float4 vv = *(const float4*)&S[row * 516 + c0 + i2 * 4];
      m = fmaxf(m, fmaxf(fmaxf(vv.x, vv.y), fmaxf(vv.z, vv.w)));
    }
    #pragma unroll
    for (int o = 1; o < 16; o <<= 1) m = fmaxf(m, __shfl_xor(m, o));
    float sum = 0.f;
    #pragma unroll
    for (int i2 = 0; i2 < 8; ++i2) {
      float4 vv = *(const float4*)&S[row * 516 + c0 + i2 * 4];
      vv.x = expf(vv.x - m); vv.y = expf(vv.y - m);
      vv.z = expf(vv.z - m); vv.w = expf(vv.w - m);
      sum += vv.x + vv.y + vv.z + vv.w;
      *(float4*)&S[row * 516 + c0 + i2 * 4] = vv;
    }
    #pragma unroll
    for (int o = 1; o < 16; o <<= 1) sum += __shfl_xor(sum, o);
    if ((tid & 15) == 0) rowinv[row] = 1.0f / sum;
  }
  __syncthreads();

  // phase 3: out = P @ V ; wave w owns output cols [w*16, w*16+16)
  {
    const int n0 = w * 16;
    float rinv = rowinv[lr];
    f32x4 acc = (f32x4){0.f, 0.f, 0.f, 0.f};
    #pragma unroll
    for (int ks = 0; ks < 16; ++ks) {
      float4 p0 = *(const float4*)&S[lr * 516 + ks * 32 + lk];
      float4 p1 = *(const float4*)&S[lr * 516 + ks * 32 + lk + 4];
      union { u16x8 u; bfx8 b; } pa;
      pa.u[0] = f2bf(p0.x * rinv); pa.u[1] = f2bf(p0.y * rinv);
      pa.u[2] = f2bf(p0.z * rinv); pa.u[3] = f2bf(p0.w * rinv);
      pa.u[4] = f2bf(p1.x * rinv); pa.u[5] = f2bf(p1.y * rinv);
      pa.u[6] = f2bf(p1.z * rinv); pa.u[7] = f2bf(p1.w * rinv);
      bfx8 vf = *(const bfx8*)(vT + ((size_t)bh * DK_ + n0 + lr) * T_ + ks * 32 + lk);
      acc = __builtin_amdgcn_mfma_f32_16x16x32_bf16(pa.b, vf, acc, 0, 0, 0);
    }
    #pragma unroll
    for (int r = 0; r < 4; ++r) {
      int i = i0 + (lane >> 4) * 4 + r;
      ao[((size_t)b * T_ + i) * D_ + h * DK_ + n0 + lr] = f2bf(acc[r]);
    }
  }
}

extern "C" void kernel_launch(void* const* d_in, const int* in_sizes, int n_in,
                              void* d_out, int out_size, void* d_ws, size_t ws_size,
                              hipStream_t stream) {
  (void)in_sizes; (void)n_in; (void)out_size; (void)ws_size;
  const float* x    = (const float*)d_in[0];
  const float* tmat = (const float*)d_in[1];
  const int*   pad  = (const int*)d_in[2];
  const float* wq = (const float*)d_in[3];  const float* bq = (const float*)d_in[4];
  const float* wk = (const float*)d_in[5];  const float* bk = (const float*)d_in[6];
  const float* wv = (const float*)d_in[7];  const float* bv = (const float*)d_in[8];
  const float* wp = (const float*)d_in[9];  const float* bp = (const float*)d_in[10];
  const float* tb1w = (const float*)d_in[11]; const float* tb1b = (const float*)d_in[12];
  const float* tb2w = (const float*)d_in[13]; const float* tb2b = (const float*)d_in[14];
  const float* fc1w = (const float*)d_in[15]; const float* fc1b = (const float*)d_in[16];
  const float* fc2w = (const float*)d_in[17]; const float* fc2b = (const float*)d_in[18];
  const float* ln1g = (const float*)d_in[19]; const float* ln1b = (const float*)d_in[20];
  const float* ln2g = (const float*)d_in[21]; const float* ln2b = (const float*)d_in[22];
  float* out = (float*)d_out;

  char* p = (char*)d_ws;
  u16* wqT  = (u16*)p; p += (size_t)768 * 768 * 2;
  u16* wkT  = (u16*)p; p += (size_t)768 * 768 * 2;
  u16* wvT  = (u16*)p; p += (size_t)768 * 768 * 2;
  u16* wpT  = (u16*)p; p += (size_t)768 * 768 * 2;
  u16* fc1T = (u16*)p; p += (size_t)768 * 3072 * 2;
  u16* fc2T = (u16*)p; p += (size_t)3072 * 768 * 2;
  u16* hbuf = (u16*)p; p += (size_t)NTOK * D_ * 2;
  u16* qb   = (u16*)p; p += (size_t)NTOK * D_ * 2;
  u16* kb   = (u16*)p; p += (size_t)NTOK * D_ * 2;
  u16* vTb  = (u16*)p; p += (size_t)NTOK * D_ * 2;
  float* biasM = (float*)p; p += (size_t)B_ * T_ * T_ * 4;
  u16* ao   = (u16*)p; p += (size_t)NTOK * D_ * 2;
  float* x1 = (float*)p; p += (size_t)NTOK * D_ * 4;
  u16* h2   = (u16*)p; p += (size_t)NTOK * D_ * 2;
  u16* gbuf = (u16*)p; p += (size_t)NTOK * FF_ * 2;

  dim3 tpb(32, 8);
  transpose_cast<<<dim3(24, 24), tpb, 0, stream>>>(wq, wqT, 768, 768);
  transpose_cast<<<dim3(24, 24), tpb, 0, stream>>>(wk, wkT, 768, 768);
  transpose_cast<<<dim3(24, 24), tpb, 0, stream>>>(wv, wvT, 768, 768);
  transpose_cast<<<dim3(24, 24), tpb, 0, stream>>>(wp, wpT, 768, 768);
  transpose_cast<<<dim3(96, 24), tpb, 0, stream>>>(fc1w, fc1T, 768, 3072);
  transpose_cast<<<dim3(24, 96), tpb, 0, stream>>>(fc2w, fc2T, 3072, 768);

  ln_cast<<<NTOK, 256, 0, stream>>>(x, ln1g, ln1b, hbuf);
  bias_mlp<<<(B_ * T_ * T_) / 256, 256, 0, stream>>>(tmat, pad, tb1w, tb1b, tb2w, tb2b, biasM);

  gemm_qkv<<<dim3(6, 16, 3), 256, 0, stream>>>(hbuf, wqT, wkT, wvT, bq, bk, bv, qb, kb, vTb);
  attn_kernel<<<dim3(T_ / 16, B_ * H_), 256, 0, stream>>>(qb, kb, vTb, biasM, ao);

  gemm_bt<2><<<dim3(6, 16), 256, 0, stream>>>(ao, wpT, bp, x, x1, NTOK, 768, 768, 1.0f);
  ln_cast<<<NTOK, 256, 0, stream>>>(x1, ln2g, ln2b, h2);
  gemm_bt<3><<<dim3(24, 16), 256, 0, stream>>>(h2, fc1T, fc1b, nullptr, gbuf, NTOK, FF_, 768, 1.0f);
  gemm_bt<2><<<dim3(6, 16), 256, 0, stream>>>(gbuf, fc2T, fc2b, x1, out, NTOK, 768, FF_, 1.0f);
}

// Round 2
// 182.957 us; speedup vs baseline: 1.2624x; 1.2624x over previous
//
#include <hip/hip_runtime.h>
#include <hip/hip_bf16.h>
#include <math.h>

#define B_ 4
#define T_ 512
#define D_ 768
#define H_ 12
#define FF_ 3072
#define DK_ 64
#define NTOK (B_*T_)
#define NEGV -1e9f

typedef unsigned short u16;
typedef __bf16 bfx8 __attribute__((ext_vector_type(8)));
typedef float f32x4 __attribute__((ext_vector_type(4)));
typedef u16 u16x8 __attribute__((ext_vector_type(8)));

__device__ __forceinline__ u16 f2bf(float f) {
  union { float f; unsigned u; } v; v.f = f;
  unsigned r = (v.u + 0x7FFFu + ((v.u >> 16) & 1u)) >> 16;   // RNE
  return (u16)r;
}

__device__ __forceinline__ void glds16(const u16* g, u16* l) {
  __builtin_amdgcn_global_load_lds((const __attribute__((address_space(1))) void*)g,
                                   (__attribute__((address_space(3))) void*)l, 16, 0, 0);
}

// ---------------- weight transpose + cast:  in (K,N) f32  ->  out (N,K) bf16
__global__ void transpose_cast(const float* __restrict__ in, u16* __restrict__ out, int K, int N)
{
  __shared__ float tile[32][33];
  int n0 = blockIdx.x * 32, k0 = blockIdx.y * 32;
  int tx = threadIdx.x, ty = threadIdx.y;   // (32,8)
  #pragma unroll
  for (int i = 0; i < 4; ++i) {
    int r = ty + i * 8;
    tile[r][tx] = in[(size_t)(k0 + r) * N + n0 + tx];
  }
  __syncthreads();
  #pragma unroll
  for (int i = 0; i < 4; ++i) {
    int r = ty + i * 8;
    out[(size_t)(n0 + r) * K + k0 + tx] = f2bf(tile[tx][r]);
  }
}

// ---------------- LayerNorm (row = 768) -> bf16 (LN1)
__global__ __launch_bounds__(256) void ln_cast(const float* __restrict__ x, const float* __restrict__ g,
                                               const float* __restrict__ b, u16* __restrict__ out)
{
  const int row = blockIdx.x;
  const int tid = threadIdx.x;
  const float* xr = x + (size_t)row * D_;
  float v0 = xr[tid], v1 = xr[tid + 256], v2 = xr[tid + 512];
  float s = v0 + v1 + v2;
  float sq = v0 * v0 + v1 * v1 + v2 * v2;
  #pragma unroll
  for (int o = 32; o > 0; o >>= 1) { s += __shfl_down(s, o); sq += __shfl_down(sq, o); }
  __shared__ float ss[4], s2[4];
  int w = tid >> 6;
  if ((tid & 63) == 0) { ss[w] = s; s2[w] = sq; }
  __syncthreads();
  s = ss[0] + ss[1] + ss[2] + ss[3];
  sq = s2[0] + s2[1] + s2[2] + s2[3];
  float mean = s * (1.0f / 768.0f);
  float inv = rsqrtf(sq * (1.0f / 768.0f) - mean * mean + 1e-5f);
  u16* orow = out + (size_t)row * D_;
  orow[tid]       = f2bf((v0 - mean) * inv * g[tid]       + b[tid]);
  orow[tid + 256] = f2bf((v1 - mean) * inv * g[tid + 256] + b[tid + 256]);
  orow[tid + 512] = f2bf((v2 - mean) * inv * g[tid + 512] + b[tid + 512]);
}

// ---------------- temporal bias MLP (+ padding mask), per (b,i,j), fp32
__global__ __launch_bounds__(256) void bias_mlp(const float* __restrict__ tmat, const int* __restrict__ pad,
    const float* __restrict__ w1, const float* __restrict__ b1,
    const float* __restrict__ w2, const float* __restrict__ b2,
    float* __restrict__ biasM)
{
  __shared__ float sw1[64], sb1[64], sw2[64];
  if (threadIdx.x < 64) {
    sw1[threadIdx.x] = w1[threadIdx.x];
    sb1[threadIdx.x] = b1[threadIdx.x];
    sw2[threadIdx.x] = w2[threadIdx.x];
  }
  __syncthreads();
  size_t idx = (size_t)blockIdx.x * 256 + threadIdx.x;   // over B*T*T
  float tm = 1.0f / logf(2.718281828459045f + tmat[idx]);
  float acc = b2[0];
  #pragma unroll
  for (int t = 0; t < 64; ++t) {
    float u = fmaf(tm, sw1[t], sb1[t]);
    u = u > 0.0f ? u : 0.2f * u;          // leaky_relu(0.2)
    acc = fmaf(u, sw2[t], acc);
  }
  biasM[idx] = (pad[idx] == 0) ? NEGV : acc;   // (B,1,T,T): same flat index
}

// ---------------- m97-style GEMM mainloop: linear LDS + global_load_lds(16B)
// C(M,N) = A(M,K) * BT(N,K)^T over k in [k0, k0+32*nk), 128x128 tile
__device__ __forceinline__ void gemm_tile_glds(
    const u16* __restrict__ A, const u16* __restrict__ BT,
    int K, int nk, int m0, int n0, int k0,
    u16* As, u16* Bs, f32x4 acc[4][4])
{
  const int tid = threadIdx.x;
  const int w = tid >> 6, lane = tid & 63;
  const int lr = lane & 15, lk = (lane >> 4) * 8;
  const int wm = (w >> 1) * 64, wn = (w & 1) * 64;
  // chunk c = i*256 + w*64 + lane covers LDS bytes [c*16, c*16+16)
  const int c0 = w * 64 + lane, c1 = 256 + c0;
  const int r0 = c0 >> 2, o0 = (c0 & 3) * 8;
  const int r1 = c1 >> 2, o1 = (c1 & 3) * 8;
  const u16* ga0 = A  + (size_t)(m0 + r0) * K + k0 + o0;
  const u16* ga1 = A  + (size_t)(m0 + r1) * K + k0 + o1;
  const u16* gb0 = BT + (size_t)(n0 + r0) * K + k0 + o0;
  const u16* gb1 = BT + (size_t)(n0 + r1) * K + k0 + o1;
  u16* la0 = As + w * 512;           // wave-uniform LDS bases (lane*16 added by HW)
  u16* la1 = As + 2048 + w * 512;
  u16* lb0 = Bs + w * 512;
  u16* lb1 = Bs + 2048 + w * 512;
  for (int kt = 0; kt < nk; ++kt) {
    glds16(ga0, la0); glds16(ga1, la1);
    glds16(gb0, lb0); glds16(gb1, lb1);
    ga0 += 32; ga1 += 32; gb0 += 32; gb1 += 32;
    __syncthreads();
    bfx8 af[4], bfr[4];
    #pragma unroll
    for (int t = 0; t < 4; ++t) {
      af[t]  = *(const bfx8*)&As[(wm + t * 16 + lr) * 32 + lk];
      bfr[t] = *(const bfx8*)&Bs[(wn + t * 16 + lr) * 32 + lk];
    }
    #pragma unroll
    for (int rt = 0; rt < 4; ++rt)
      #pragma unroll
      for (int ct = 0; ct < 4; ++ct)
        acc[rt][ct] = __builtin_amdgcn_mfma_f32_16x16x32_bf16(af[rt], bfr[ct], acc[rt][ct], 0, 0, 0);
    __syncthreads();
  }
}

// QKV fused over blockIdx.z (0=q,1=k,2=v)
__global__ __launch_bounds__(256) void gemm_qkv(
    const u16* __restrict__ A,
    const u16* __restrict__ wqT, const u16* __restrict__ wkT, const u16* __restrict__ wvT,
    const float* __restrict__ bq, const float* __restrict__ bk, const float* __restrict__ bv,
    u16* __restrict__ qo, u16* __restrict__ ko, u16* __restrict__ vo)
{
  __shared__ u16 As[128 * 32];
  __shared__ u16 Bs[128 * 32];
  const int z = blockIdx.z;
  const u16* BT = z == 0 ? wqT : (z == 1 ? wkT : wvT);
  const float* bias = z == 0 ? bq : (z == 1 ? bk : bv);
  u16* outp = z == 0 ? qo : (z == 1 ? ko : vo);
  const float scale = z == 0 ? 0.125f : 1.0f;   // DK^-0.5 folded into q
  const int m0 = blockIdx.y * 128, n0 = blockIdx.x * 128;
  f32x4 acc[4][4];
  #pragma unroll
  for (int a = 0; a < 4; ++a)
    #pragma unroll
    for (int bb = 0; bb < 4; ++bb) acc[a][bb] = (f32x4){0.f, 0.f, 0.f, 0.f};
  gemm_tile_glds(A, BT, D_, D_ / 32, m0, n0, 0, As, Bs, acc);
  const int tid = threadIdx.x;
  const int w = tid >> 6, lane = tid & 63;
  const int lr = lane & 15;
  const int wm = (w >> 1) * 64, wn = (w & 1) * 64;
  #pragma unroll
  for (int rt = 0; rt < 4; ++rt)
    #pragma unroll
    for (int ct = 0; ct < 4; ++ct)
      #pragma unroll
      for (int r = 0; r < 4; ++r) {
        int m = m0 + wm + rt * 16 + (lane >> 4) * 4 + r;
        int n = n0 + wn + ct * 16 + lr;
        float val = (acc[rt][ct][r] + bias[n]) * scale;
        int b = m >> 9, t = m & 511, hh = n >> 6, d = n & 63;
        if (z < 2) outp[(((size_t)b * H_ + hh) * T_ + t) * DK_ + d] = f2bf(val);
        else       outp[(((size_t)b * H_ + hh) * DK_ + d) * T_ + t] = f2bf(val);
      }
}

// split-K GEMM -> fp32 partials part[kz][M][N]
__global__ __launch_bounds__(256) void gemm_part(
    const u16* __restrict__ A, const u16* __restrict__ BT,
    float* __restrict__ part, int M, int N, int K, int Ksplit)
{
  __shared__ u16 As[128 * 32];
  __shared__ u16 Bs[128 * 32];
  const int m0 = blockIdx.y * 128, n0 = blockIdx.x * 128;
  const int kz = blockIdx.z;
  f32x4 acc[4][4];
  #pragma unroll
  for (int a = 0; a < 4; ++a)
    #pragma unroll
    for (int bb = 0; bb < 4; ++bb) acc[a][bb] = (f32x4){0.f, 0.f, 0.f, 0.f};
  gemm_tile_glds(A, BT, K, Ksplit / 32, m0, n0, kz * Ksplit, As, Bs, acc);
  const int tid = threadIdx.x;
  const int w = tid >> 6, lane = tid & 63;
  const int lr = lane & 15;
  const int wm = (w >> 1) * 64, wn = (w & 1) * 64;
  float* pp = part + (size_t)kz * M * N;
  #pragma unroll
  for (int rt = 0; rt < 4; ++rt)
    #pragma unroll
    for (int ct = 0; ct < 4; ++ct)
      #pragma unroll
      for (int r = 0; r < 4; ++r) {
        int m = m0 + wm + rt * 16 + (lane >> 4) * 4 + r;
        int n = n0 + wn + ct * 16 + lr;
        pp[(size_t)m * N + n] = acc[rt][ct][r];
      }
}

// FFN1: gelu epilogue -> bf16
__global__ __launch_bounds__(256) void gemm_gelu(
    const u16* __restrict__ A, const u16* __restrict__ BT,
    const float* __restrict__ bias, u16* __restrict__ outp, int M, int N, int K)
{
  __shared__ u16 As[128 * 32];
  __shared__ u16 Bs[128 * 32];
  const int m0 = blockIdx.y * 128, n0 = blockIdx.x * 128;
  f32x4 acc[4][4];
  #pragma unroll
  for (int a = 0; a < 4; ++a)
    #pragma unroll
    for (int bb = 0; bb < 4; ++bb) acc[a][bb] = (f32x4){0.f, 0.f, 0.f, 0.f};
  gemm_tile_glds(A, BT, K, K / 32, m0, n0, 0, As, Bs, acc);
  const int tid = threadIdx.x;
  const int w = tid >> 6, lane = tid & 63;
  const int lr = lane & 15;
  const int wm = (w >> 1) * 64, wn = (w & 1) * 64;
  #pragma unroll
  for (int rt = 0; rt < 4; ++rt)
    #pragma unroll
    for (int ct = 0; ct < 4; ++ct)
      #pragma unroll
      for (int r = 0; r < 4; ++r) {
        int m = m0 + wm + rt * 16 + (lane >> 4) * 4 + r;
        int n = n0 + wn + ct * 16 + lr;
        float val = acc[rt][ct][r] + bias[n];
        float gl = 0.5f * val * (1.0f + erff(val * 0.7071067811865475f));
        outp[(size_t)m * N + n] = f2bf(gl);
      }
}

// proj reduce (2 partials) + residual + bias, then fused LN2 -> x1 (f32) + h2 (bf16)
__global__ __launch_bounds__(256) void reduce_ln(
    const float* __restrict__ part, const float* __restrict__ x, const float* __restrict__ bp,
    const float* __restrict__ g, const float* __restrict__ bta,
    float* __restrict__ x1, u16* __restrict__ h2)
{
  const int row = blockIdx.x;
  const int tid = threadIdx.x;
  const size_t base = (size_t)row * D_;
  const size_t slab = (size_t)NTOK * D_;
  float v[3];
  float s = 0.f, sq = 0.f;
  #pragma unroll
  for (int i = 0; i < 3; ++i) {
    int c = tid + i * 256;
    float val = x[base + c] + bp[c] + part[base + c] + part[slab + base + c];
    v[i] = val;
    s += val; sq += val * val;
  }
  #pragma unroll
  for (int o = 32; o > 0; o >>= 1) { s += __shfl_down(s, o); sq += __shfl_down(sq, o); }
  __shared__ float ss[4], s2[4];
  int w = tid >> 6;
  if ((tid & 63) == 0) { ss[w] = s; s2[w] = sq; }
  __syncthreads();
  s = ss[0] + ss[1] + ss[2] + ss[3];
  sq = s2[0] + s2[1] + s2[2] + s2[3];
  float mean = s * (1.0f / 768.0f);
  float inv = rsqrtf(sq * (1.0f / 768.0f) - mean * mean + 1e-5f);
  #pragma unroll
  for (int i = 0; i < 3; ++i) {
    int c = tid + i * 256;
    x1[base + c] = v[i];
    h2[base + c] = f2bf((v[i] - mean) * inv * g[c] + bta[c]);
  }
}

// FFN2 reduce (4 partials) + residual + bias -> out f32, float4-vectorized
__global__ __launch_bounds__(256) void reduce_out(
    const float* __restrict__ part, const float* __restrict__ x1,
    const float* __restrict__ bias, float* __restrict__ out)
{
  const size_t i = (size_t)blockIdx.x * 256 + threadIdx.x;   // over NTOK*D/4
  const size_t slab = (size_t)NTOK * D_ / 4;
  float4 b = ((const float4*)bias)[i % (D_ / 4)];
  float4 a = ((const float4*)x1)[i];
  float4 p0 = ((const float4*)part)[i];
  float4 p1 = ((const float4*)part)[i + slab];
  float4 p2 = ((const float4*)part)[i + 2 * slab];
  float4 p3 = ((const float4*)part)[i + 3 * slab];
  float4 o;
  o.x = a.x + b.x + p0.x + p1.x + p2.x + p3.x;
  o.y = a.y + b.y + p0.y + p1.y + p2.y + p3.y;
  o.z = a.z + b.z + p0.z + p1.z + p2.z + p3.z;
  o.w = a.w + b.w + p0.w + p1.w + p2.w + p3.w;
  ((float4*)out)[i] = o;
}

// ---------------- attention: block = (b,h) x 16 q-rows; S strip in LDS
__global__ __launch_bounds__(256) void attn_kernel(
    const u16* __restrict__ q, const u16* __restrict__ k, const u16* __restrict__ vT,
    const float* __restrict__ biasM, u16* __restrict__ ao)
{
  __shared__ float S[16 * 516];          // 16 rows x 512 cols, +4 pad
  __shared__ float rowinv[16];
  const int tid = threadIdx.x;
  const int w = tid >> 6, lane = tid & 63;
  const int lr = lane & 15, lk = (lane >> 4) * 8;
  const int bh = blockIdx.y;             // b*H + h
  const int b = bh / H_, h = bh % H_;
  const int i0 = blockIdx.x * 16;

  // phase 1: S = (q*scale) k^T + bias, causal-masked
  bfx8 qf[2];
  #pragma unroll
  for (int ks = 0; ks < 2; ++ks)
    qf[ks] = *(const bfx8*)(q + ((size_t)bh * T_ + i0 + lr) * DK_ + ks * 32 + lk);
  const int jbase = w * 128;
  #pragma unroll
  for (int ct = 0; ct < 8; ++ct) {
    int j0 = jbase + ct * 16;
    bfx8 kf0 = *(const bfx8*)(k + ((size_t)bh * T_ + j0 + lr) * DK_ + lk);
    bfx8 kf1 = *(const bfx8*)(k + ((size_t)bh * T_ + j0 + lr) * DK_ + 32 + lk);
    f32x4 acc = (f32x4){0.f, 0.f, 0.f, 0.f};
    acc = __builtin_amdgcn_mfma_f32_16x16x32_bf16(qf[0], kf0, acc, 0, 0, 0);
    acc = __builtin_amdgcn_mfma_f32_16x16x32_bf16(qf[1], kf1, acc, 0, 0, 0);
    int j = j0 + lr;
    #pragma unroll
    for (int r = 0; r < 4; ++r) {
      int il = (lane >> 4) * 4 + r;
      int i = i0 + il;
      float s = acc[r] + biasM[((size_t)b * T_ + i) * T_ + j];
      if (j > i && i != 0) s = NEGV;     // causal, CLS row 0 fully visible
      S[il * 516 + j0 + lr] = s;
    }
  }
  __syncthreads();

  // phase 2: row softmax (16 lanes per row, 32 cols each)
  {
    int row = tid >> 4;
    int c0 = (tid & 15) * 32;
    float m = -3.4e38f;
    #pragma unroll
    for (int i2 = 0; i2 < 8; ++i2) {
      float4 vv = *(const float4*)&S[row * 516 + c0 + i2 * 4];
      m = fmaxf(m, fmaxf(fmaxf(vv.x, vv.y), fmaxf(vv.z, vv.w)));
    }
    #pragma unroll
    for (int o = 1; o < 16; o <<= 1) m = fmaxf(m, __shfl_xor(m, o));
    float sum = 0.f;
    #pragma unroll
    for (int i2 = 0; i2 < 8; ++i2) {
      float4 vv = *(const float4*)&S[row * 516 + c0 + i2 * 4];
      vv.x = expf(vv.x - m); vv.y = expf(vv.y - m);
      vv.z = expf(vv.z - m); vv.w = expf(vv.w - m);
      sum += vv.x + vv.y + vv.z + vv.w;
      *(float4*)&S[row * 516 + c0 + i2 * 4] = vv;
    }
    #pragma unroll
    for (int o = 1; o < 16; o <<= 1) sum += __shfl_xor(sum, o);
    if ((tid & 15) == 0) rowinv[row] = 1.0f / sum;
  }
  __syncthreads();

  // phase 3: out = P @ V ; wave w owns output cols [w*16, w*16+16)
  {
    const int n0 = w * 16;
    float rinv = rowinv[lr];
    f32x4 acc = (f32x4){0.f, 0.f, 0.f, 0.f};
    #pragma unroll
    for (int ks = 0; ks < 16; ++ks) {
      float4 p0 = *(const float4*)&S[lr * 516 + ks * 32 + lk];
      float4 p1 = *(const float4*)&S[lr * 516 + ks * 32 + lk + 4];
      union { u16x8 u; bfx8 b; } pa;
      pa.u[0] = f2bf(p0.x * rinv); pa.u[1] = f2bf(p0.y * rinv);
      pa.u[2] = f2bf(p0.z * rinv); pa.u[3] = f2bf(p0.w * rinv);
      pa.u[4] = f2bf(p1.x * rinv); pa.u[5] = f2bf(p1.y * rinv);
      pa.u[6] = f2bf(p1.z * rinv); pa.u[7] = f2bf(p1.w * rinv);
      bfx8 vf = *(const bfx8*)(vT + ((size_t)bh * DK_ + n0 + lr) * T_ + ks * 32 + lk);
      acc = __builtin_amdgcn_mfma_f32_16x16x32_bf16(pa.b, vf, acc, 0, 0, 0);
    }
    #pragma unroll
    for (int r = 0; r < 4; ++r) {
      int i = i0 + (lane >> 4) * 4 + r;
      ao[((size_t)b * T_ + i) * D_ + h * DK_ + n0 + lr] = f2bf(acc[r]);
    }
  }
}

extern "C" void kernel_launch(void* const* d_in, const int* in_sizes, int n_in,
                              void* d_out, int out_size, void* d_ws, size_t ws_size,
                              hipStream_t stream) {
  (void)in_sizes; (void)n_in; (void)out_size; (void)ws_size;
  const float* x    = (const float*)d_in[0];
  const float* tmat = (const float*)d_in[1];
  const int*   pad  = (const int*)d_in[2];
  const float* wq = (const float*)d_in[3];  const float* bq = (const float*)d_in[4];
  const float* wk = (const float*)d_in[5];  const float* bk = (const float*)d_in[6];
  const float* wv = (const float*)d_in[7];  const float* bv = (const float*)d_in[8];
  const float* wp = (const float*)d_in[9];  const float* bp = (const float*)d_in[10];
  const float* tb1w = (const float*)d_in[11]; const float* tb1b = (const float*)d_in[12];
  const float* tb2w = (const float*)d_in[13]; const float* tb2b = (const float*)d_in[14];
  const float* fc1w = (const float*)d_in[15]; const float* fc1b = (const float*)d_in[16];
  const float* fc2w = (const float*)d_in[17]; const float* fc2b = (const float*)d_in[18];
  const float* ln1g = (const float*)d_in[19]; const float* ln1b = (const float*)d_in[20];
  const float* ln2g = (const float*)d_in[21]; const float* ln2b = (const float*)d_in[22];
  float* out = (float*)d_out;

  // ---- workspace layout (with aliasing of dead buffers onto split-K partials)
  char* p = (char*)d_ws;
  u16* wqT  = (u16*)p; p += (size_t)768 * 768 * 2;
  u16* wkT  = (u16*)p; p += (size_t)768 * 768 * 2;
  u16* wvT  = (u16*)p; p += (size_t)768 * 768 * 2;
  u16* wpT  = (u16*)p; p += (size_t)768 * 768 * 2;
  u16* fc1T = (u16*)p; p += (size_t)768 * 3072 * 2;
  u16* fc2T = (u16*)p; p += (size_t)3072 * 768 * 2;
  float* x1 = (float*)p; p += (size_t)NTOK * D_ * 4;
  u16* gbuf = (u16*)p; p += (size_t)NTOK * FF_ * 2;
  char* pool = p;   // 25165824-byte overlay pool
  u16*   hbuf  = (u16*)(pool + 0);
  u16*   qb    = (u16*)(pool + 3145728);
  u16*   kb    = (u16*)(pool + 6291456);
  u16*   vTb   = (u16*)(pool + 9437184);
  float* biasM = (float*)(pool + 12582912);
  u16*   ao    = (u16*)(pool + 16777216);
  u16*   h2    = (u16*)(pool + 19922944);
  float* partP = (float*)(pool + 0);   // proj split-2 partials (12.6 MB) — qb/kb/vTb/hbuf dead
  float* partF = (float*)(pool + 0);   // ffn2 split-4 partials (25.2 MB) — whole pool dead

  dim3 tpb(32, 8);
  transpose_cast<<<dim3(24, 24), tpb, 0, stream>>>(wq, wqT, 768, 768);
  transpose_cast<<<dim3(24, 24), tpb, 0, stream>>>(wk, wkT, 768, 768);
  transpose_cast<<<dim3(24, 24), tpb, 0, stream>>>(wv, wvT, 768, 768);
  transpose_cast<<<dim3(24, 24), tpb, 0, stream>>>(wp, wpT, 768, 768);
  transpose_cast<<<dim3(96, 24), tpb, 0, stream>>>(fc1w, fc1T, 768, 3072);
  transpose_cast<<<dim3(24, 96), tpb, 0, stream>>>(fc2w, fc2T, 3072, 768);

  ln_cast<<<NTOK, 256, 0, stream>>>(x, ln1g, ln1b, hbuf);
  bias_mlp<<<(B_ * T_ * T_) / 256, 256, 0, stream>>>(tmat, pad, tb1w, tb1b, tb2w, tb2b, biasM);

  gemm_qkv<<<dim3(6, 16, 3), 256, 0, stream>>>(hbuf, wqT, wkT, wvT, bq, bk, bv, qb, kb, vTb);
  attn_kernel<<<dim3(T_ / 16, B_ * H_), 256, 0, stream>>>(qb, kb, vTb, biasM, ao);

  // proj: split-K=2 (192 blocks), then reduce fused with LN2
  gemm_part<<<dim3(6, 16, 2), 256, 0, stream>>>(ao, wpT, partP, NTOK, 768, 768, 384);
  reduce_ln<<<NTOK, 256, 0, stream>>>(partP, x, bp, ln2g, ln2b, x1, h2);

  // FFN1 (384 blocks)
  gemm_gelu<<<dim3(24, 16), 256, 0, stream>>>(h2, fc1T, fc1b, gbuf, NTOK, FF_, 768);

  // FFN2: split-K=4 (384 blocks), then reduce + residual
  gemm_part<<<dim3(6, 16, 4), 256, 0, stream>>>(gbuf, fc2T, partF, NTOK, 768, 3072, 768);
  reduce_out<<<NTOK * D_ / 4 / 256, 256, 0, stream>>>(partF, x1, fc2b, out);
}

// Round 3
// 175.168 us; speedup vs baseline: 1.3186x; 1.0445x over previous
//
#include <hip/hip_runtime.h>
#include <hip/hip_bf16.h>
#include <math.h>

#define B_ 4
#define T_ 512
#define D_ 768
#define H_ 12
#define FF_ 3072
#define DK_ 64
#define NTOK (B_*T_)
#define NEGV -1e9f

typedef unsigned short u16;
typedef __bf16 bfx8 __attribute__((ext_vector_type(8)));
typedef float f32x4 __attribute__((ext_vector_type(4)));
typedef u16 u16x8 __attribute__((ext_vector_type(8)));

__device__ __forceinline__ u16 f2bf(float f) {
  union { float f; unsigned u; } v; v.f = f;
  unsigned r = (v.u + 0x7FFFu + ((v.u >> 16) & 1u)) >> 16;   // RNE
  return (u16)r;
}

__device__ __forceinline__ void glds16(const u16* g, u16* l) {
  __builtin_amdgcn_global_load_lds((const __attribute__((address_space(1))) void*)g,
                                   (__attribute__((address_space(3))) void*)l, 16, 0, 0);
}

// ---------------- weight transpose + cast:  in (K,N) f32  ->  out (N,K) bf16
__global__ void transpose_cast(const float* __restrict__ in, u16* __restrict__ out, int K, int N)
{
  __shared__ float tile[32][33];
  int n0 = blockIdx.x * 32, k0 = blockIdx.y * 32;
  int tx = threadIdx.x, ty = threadIdx.y;   // (32,8)
  #pragma unroll
  for (int i = 0; i < 4; ++i) {
    int r = ty + i * 8;
    tile[r][tx] = in[(size_t)(k0 + r) * N + n0 + tx];
  }
  __syncthreads();
  #pragma unroll
  for (int i = 0; i < 4; ++i) {
    int r = ty + i * 8;
    out[(size_t)(n0 + r) * K + k0 + tx] = f2bf(tile[tx][r]);
  }
}

// ---------------- LayerNorm (row = 768) -> bf16 (LN1)
__global__ __launch_bounds__(256) void ln_cast(const float* __restrict__ x, const float* __restrict__ g,
                                               const float* __restrict__ b, u16* __restrict__ out)
{
  const int row = blockIdx.x;
  const int tid = threadIdx.x;
  const float* xr = x + (size_t)row * D_;
  float v0 = xr[tid], v1 = xr[tid + 256], v2 = xr[tid + 512];
  float s = v0 + v1 + v2;
  float sq = v0 * v0 + v1 * v1 + v2 * v2;
  #pragma unroll
  for (int o = 32; o > 0; o >>= 1) { s += __shfl_down(s, o); sq += __shfl_down(sq, o); }
  __shared__ float ss[4], s2[4];
  int w = tid >> 6;
  if ((tid & 63) == 0) { ss[w] = s; s2[w] = sq; }
  __syncthreads();
  s = ss[0] + ss[1] + ss[2] + ss[3];
  sq = s2[0] + s2[1] + s2[2] + s2[3];
  float mean = s * (1.0f / 768.0f);
  float inv = rsqrtf(sq * (1.0f / 768.0f) - mean * mean + 1e-5f);
  u16* orow = out + (size_t)row * D_;
  orow[tid]       = f2bf((v0 - mean) * inv * g[tid]       + b[tid]);
  orow[tid + 256] = f2bf((v1 - mean) * inv * g[tid + 256] + b[tid + 256]);
  orow[tid + 512] = f2bf((v2 - mean) * inv * g[tid + 512] + b[tid + 512]);
}

// ---------------- temporal bias MLP (+ padding mask), per (b,i,j), fp32
__global__ __launch_bounds__(256) void bias_mlp(const float* __restrict__ tmat, const int* __restrict__ pad,
    const float* __restrict__ w1, const float* __restrict__ b1,
    const float* __restrict__ w2, const float* __restrict__ b2,
    float* __restrict__ biasM)
{
  __shared__ float sw1[64], sb1[64], sw2[64];
  if (threadIdx.x < 64) {
    sw1[threadIdx.x] = w1[threadIdx.x];
    sb1[threadIdx.x] = b1[threadIdx.x];
    sw2[threadIdx.x] = w2[threadIdx.x];
  }
  __syncthreads();
  size_t idx = (size_t)blockIdx.x * 256 + threadIdx.x;   // over B*T*T
  float tm = 1.0f / logf(2.718281828459045f + tmat[idx]);
  float acc = b2[0];
  #pragma unroll
  for (int t = 0; t < 64; ++t) {
    float u = fmaf(tm, sw1[t], sb1[t]);
    u = u > 0.0f ? u : 0.2f * u;          // leaky_relu(0.2)
    acc = fmaf(u, sw2[t], acc);
  }
  biasM[idx] = (pad[idx] == 0) ? NEGV : acc;   // (B,1,T,T): same flat index
}

// ---------------- m97-style GEMM mainloop: linear LDS + global_load_lds(16B)
// C(M,N) = A(M,K) * BT(N,K)^T over k in [k0, k0+32*nk), 128x128 tile
__device__ __forceinline__ void gemm_tile_glds(
    const u16* __restrict__ A, const u16* __restrict__ BT,
    int K, int nk, int m0, int n0, int k0,
    u16* As, u16* Bs, f32x4 acc[4][4])
{
  const int tid = threadIdx.x;
  const int w = tid >> 6, lane = tid & 63;
  const int lr = lane & 15, lk = (lane >> 4) * 8;
  const int wm = (w >> 1) * 64, wn = (w & 1) * 64;
  // chunk c = i*256 + w*64 + lane covers LDS bytes [c*16, c*16+16)
  const int c0 = w * 64 + lane, c1 = 256 + c0;
  const int r0 = c0 >> 2, o0 = (c0 & 3) * 8;
  const int r1 = c1 >> 2, o1 = (c1 & 3) * 8;
  const u16* ga0 = A  + (size_t)(m0 + r0) * K + k0 + o0;
  const u16* ga1 = A  + (size_t)(m0 + r1) * K + k0 + o1;
  const u16* gb0 = BT + (size_t)(n0 + r0) * K + k0 + o0;
  const u16* gb1 = BT + (size_t)(n0 + r1) * K + k0 + o1;
  u16* la0 = As + w * 512;           // wave-uniform LDS bases (lane*16 added by HW)
  u16* la1 = As + 2048 + w * 512;
  u16* lb0 = Bs + w * 512;
  u16* lb1 = Bs + 2048 + w * 512;
  for (int kt = 0; kt < nk; ++kt) {
    glds16(ga0, la0); glds16(ga1, la1);
    glds16(gb0, lb0); glds16(gb1, lb1);
    ga0 += 32; ga1 += 32; gb0 += 32; gb1 += 32;
    __syncthreads();
    bfx8 af[4], bfr[4];
    #pragma unroll
    for (int t = 0; t < 4; ++t) {
      af[t]  = *(const bfx8*)&As[(wm + t * 16 + lr) * 32 + lk];
      bfr[t] = *(const bfx8*)&Bs[(wn + t * 16 + lr) * 32 + lk];
    }
    #pragma unroll
    for (int rt = 0; rt < 4; ++rt)
      #pragma unroll
      for (int ct = 0; ct < 4; ++ct)
        acc[rt][ct] = __builtin_amdgcn_mfma_f32_16x16x32_bf16(af[rt], bfr[ct], acc[rt][ct], 0, 0, 0);
    __syncthreads();
  }
}

// QKV fused over blockIdx.z (0=q,1=k,2=v)
__global__ __launch_bounds__(256) void gemm_qkv(
    const u16* __restrict__ A,
    const u16* __restrict__ wqT, const u16* __restrict__ wkT, const u16* __restrict__ wvT,
    const float* __restrict__ bq, const float* __restrict__ bk, const float* __restrict__ bv,
    u16* __restrict__ qo, u16* __restrict__ ko, u16* __restrict__ vo)
{
  __shared__ u16 As[128 * 32];
  __shared__ u16 Bs[128 * 32];
  const int z = blockIdx.z;
  const u16* BT = z == 0 ? wqT : (z == 1 ? wkT : wvT);
  const float* bias = z == 0 ? bq : (z == 1 ? bk : bv);
  u16* outp = z == 0 ? qo : (z == 1 ? ko : vo);
  const float scale = z == 0 ? 0.125f : 1.0f;   // DK^-0.5 folded into q
  const int m0 = blockIdx.y * 128, n0 = blockIdx.x * 128;
  f32x4 acc[4][4];
  #pragma unroll
  for (int a = 0; a < 4; ++a)
    #pragma unroll
    for (int bb = 0; bb < 4; ++bb) acc[a][bb] = (f32x4){0.f, 0.f, 0.f, 0.f};
  gemm_tile_glds(A, BT, D_, D_ / 32, m0, n0, 0, As, Bs, acc);
  const int tid = threadIdx.x;
  const int w = tid >> 6, lane = tid & 63;
  const int lr = lane & 15;
  const int wm = (w >> 1) * 64, wn = (w & 1) * 64;
  #pragma unroll
  for (int rt = 0; rt < 4; ++rt)
    #pragma unroll
    for (int ct = 0; ct < 4; ++ct)
      #pragma unroll
      for (int r = 0; r < 4; ++r) {
        int m = m0 + wm + rt * 16 + (lane >> 4) * 4 + r;
        int n = n0 + wn + ct * 16 + lr;
        float val = (acc[rt][ct][r] + bias[n]) * scale;
        int b = m >> 9, t = m & 511, hh = n >> 6, d = n & 63;
        if (z < 2) outp[(((size_t)b * H_ + hh) * T_ + t) * DK_ + d] = f2bf(val);
        else       outp[(((size_t)b * H_ + hh) * DK_ + d) * T_ + t] = f2bf(val);
      }
}

// split-K GEMM -> fp32 partials part[kz][M][N]
__global__ __launch_bounds__(256) void gemm_part(
    const u16* __restrict__ A, const u16* __restrict__ BT,
    float* __restrict__ part, int M, int N, int K, int Ksplit)
{
  __shared__ u16 As[128 * 32];
  __shared__ u16 Bs[128 * 32];
  const int m0 = blockIdx.y * 128, n0 = blockIdx.x * 128;
  const int kz = blockIdx.z;
  f32x4 acc[4][4];
  #pragma unroll
  for (int a = 0; a < 4; ++a)
    #pragma unroll
    for (int bb = 0; bb < 4; ++bb) acc[a][bb] = (f32x4){0.f, 0.f, 0.f, 0.f};
  gemm_tile_glds(A, BT, K, Ksplit / 32, m0, n0, kz * Ksplit, As, Bs, acc);
  const int tid = threadIdx.x;
  const int w = tid >> 6, lane = tid & 63;
  const int lr = lane & 15;
  const int wm = (w >> 1) * 64, wn = (w & 1) * 64;
  float* pp = part + (size_t)kz * M * N;
  #pragma unroll
  for (int rt = 0; rt < 4; ++rt)
    #pragma unroll
    for (int ct = 0; ct < 4; ++ct)
      #pragma unroll
      for (int r = 0; r < 4; ++r) {
        int m = m0 + wm + rt * 16 + (lane >> 4) * 4 + r;
        int n = n0 + wn + ct * 16 + lr;
        pp[(size_t)m * N + n] = acc[rt][ct][r];
      }
}

// FFN1: gelu epilogue -> bf16
__global__ __launch_bounds__(256) void gemm_gelu(
    const u16* __restrict__ A, const u16* __restrict__ BT,
    const float* __restrict__ bias, u16* __restrict__ outp, int M, int N, int K)
{
  __shared__ u16 As[128 * 32];
  __shared__ u16 Bs[128 * 32];
  const int m0 = blockIdx.y * 128, n0 = blockIdx.x * 128;
  f32x4 acc[4][4];
  #pragma unroll
  for (int a = 0; a < 4; ++a)
    #pragma unroll
    for (int bb = 0; bb < 4; ++bb) acc[a][bb] = (f32x4){0.f, 0.f, 0.f, 0.f};
  gemm_tile_glds(A, BT, K, K / 32, m0, n0, 0, As, Bs, acc);
  const int tid = threadIdx.x;
  const int w = tid >> 6, lane = tid & 63;
  const int lr = lane & 15;
  const int wm = (w >> 1) * 64, wn = (w & 1) * 64;
  #pragma unroll
  for (int rt = 0; rt < 4; ++rt)
    #pragma unroll
    for (int ct = 0; ct < 4; ++ct)
      #pragma unroll
      for (int r = 0; r < 4; ++r) {
        int m = m0 + wm + rt * 16 + (lane >> 4) * 4 + r;
        int n = n0 + wn + ct * 16 + lr;
        float val = acc[rt][ct][r] + bias[n];
        float gl = 0.5f * val * (1.0f + erff(val * 0.7071067811865475f));
        outp[(size_t)m * N + n] = f2bf(gl);
      }
}

// proj reduce (2 partials) + residual + bias, then fused LN2 -> x1 (f32) + h2 (bf16)
__global__ __launch_bounds__(256) void reduce_ln(
    const float* __restrict__ part, const float* __restrict__ x, const float* __restrict__ bp,
    const float* __restrict__ g, const float* __restrict__ bta,
    float* __restrict__ x1, u16* __restrict__ h2)
{
  const int row = blockIdx.x;
  const int tid = threadIdx.x;
  const size_t base = (size_t)row * D_;
  const size_t slab = (size_t)NTOK * D_;
  float v[3];
  float s = 0.f, sq = 0.f;
  #pragma unroll
  for (int i = 0; i < 3; ++i) {
    int c = tid + i * 256;
    float val = x[base + c] + bp[c] + part[base + c] + part[slab + base + c];
    v[i] = val;
    s += val; sq += val * val;
  }
  #pragma unroll
  for (int o = 32; o > 0; o >>= 1) { s += __shfl_down(s, o); sq += __shfl_down(sq, o); }
  __shared__ float ss[4], s2[4];
  int w = tid >> 6;
  if ((tid & 63) == 0) { ss[w] = s; s2[w] = sq; }
  __syncthreads();
  s = ss[0] + ss[1] + ss[2] + ss[3];
  sq = s2[0] + s2[1] + s2[2] + s2[3];
  float mean = s * (1.0f / 768.0f);
  float inv = rsqrtf(sq * (1.0f / 768.0f) - mean * mean + 1e-5f);
  #pragma unroll
  for (int i = 0; i < 3; ++i) {
    int c = tid + i * 256;
    x1[base + c] = v[i];
    h2[base + c] = f2bf((v[i] - mean) * inv * g[c] + bta[c]);
  }
}

// FFN2 reduce (4 partials) + residual + bias -> out f32, float4-vectorized
__global__ __launch_bounds__(256) void reduce_out(
    const float* __restrict__ part, const float* __restrict__ x1,
    const float* __restrict__ bias, float* __restrict__ out)
{
  const size_t i = (size_t)blockIdx.x * 256 + threadIdx.x;   // over NTOK*D/4
  const size_t slab = (size_t)NTOK * D_ / 4;
  float4 b = ((const float4*)bias)[i % (D_ / 4)];
  float4 a = ((const float4*)x1)[i];
  float4 p0 = ((const float4*)part)[i];
  float4 p1 = ((const float4*)part)[i + slab];
  float4 p2 = ((const float4*)part)[i + 2 * slab];
  float4 p3 = ((const float4*)part)[i + 3 * slab];
  float4 o;
  o.x = a.x + b.x + p0.x + p1.x + p2.x + p3.x;
  o.y = a.y + b.y + p0.y + p1.y + p2.y + p3.y;
  o.z = a.z + b.z + p0.z + p1.z + p2.z + p3.z;
  o.w = a.w + b.w + p0.w + p1.w + p2.w + p3.w;
  ((float4*)out)[i] = o;
}

// ---------------- attention v2: scores in registers, P bf16 swizzled LDS
// 1-D grid, XCD-chunked: 6 bh per XCD so K/V/bias slice stays in its L2
__global__ __launch_bounds__(256) void attn_kernel(
    const u16* __restrict__ q, const u16* __restrict__ k, const u16* __restrict__ vT,
    const float* __restrict__ biasM, u16* __restrict__ ao)
{
  __shared__ u16 P[16 * 512];           // unnormalized bf16 P, XOR-swizzled
  __shared__ float pmax[64], psum[64];  // [wave][row]
  const int tid = threadIdx.x;
  const int w = tid >> 6, lane = tid & 63;
  const int lr = lane & 15, hi = lane >> 4, lk = hi * 8;

  const int bid = blockIdx.x;
  const int xcd = bid & 7, idx = bid >> 3;     // 192 blocks per XCD
  const int bh = xcd * 6 + (idx >> 5);         // 6 bh per XCD
  const int i0 = (idx & 31) * 16;
  const int b = bh / H_, h = bh % H_;

  // ---- phase 1: scores in registers. acc[ct][r] = S[row=hi*4+r][col=w*128+ct*16+lr]
  bfx8 qf[2];
  #pragma unroll
  for (int ks = 0; ks < 2; ++ks)
    qf[ks] = *(const bfx8*)(q + ((size_t)bh * T_ + i0 + lr) * DK_ + ks * 32 + lk);
  f32x4 acc[8];
  #pragma unroll
  for (int ct = 0; ct < 8; ++ct) {
    int j0 = w * 128 + ct * 16;
    bfx8 kf0 = *(const bfx8*)(k + ((size_t)bh * T_ + j0 + lr) * DK_ + lk);
    bfx8 kf1 = *(const bfx8*)(k + ((size_t)bh * T_ + j0 + lr) * DK_ + 32 + lk);
    f32x4 a0 = (f32x4){0.f, 0.f, 0.f, 0.f};
    a0 = __builtin_amdgcn_mfma_f32_16x16x32_bf16(qf[0], kf0, a0, 0, 0, 0);
    acc[ct] = __builtin_amdgcn_mfma_f32_16x16x32_bf16(qf[1], kf1, a0, 0, 0, 0);
  }

  // ---- bias + causal mask (in-register), then per-row max
  float mx[4] = {-3.4e38f, -3.4e38f, -3.4e38f, -3.4e38f};
  #pragma unroll
  for (int ct = 0; ct < 8; ++ct) {
    int j = w * 128 + ct * 16 + lr;
    #pragma unroll
    for (int r = 0; r < 4; ++r) {
      int i = i0 + hi * 4 + r;
      float s = acc[ct][r] + biasM[((size_t)b * T_ + i) * T_ + j];
      if (j > i && i != 0) s = NEGV;    // causal; CLS row 0 fully visible
      acc[ct][r] = s;
      mx[r] = fmaxf(mx[r], s);
    }
  }
  #pragma unroll
  for (int o = 1; o < 16; o <<= 1)
    #pragma unroll
    for (int r = 0; r < 4; ++r) mx[r] = fmaxf(mx[r], __shfl_xor(mx[r], o));
  if (lr == 0) {
    #pragma unroll
    for (int r = 0; r < 4; ++r) pmax[w * 16 + hi * 4 + r] = mx[r];
  }
  __syncthreads();

  // ---- exp (unnormalized) + per-row sum
  float sm[4] = {0.f, 0.f, 0.f, 0.f};
  float M[4];
  #pragma unroll
  for (int r = 0; r < 4; ++r) {
    int row = hi * 4 + r;
    M[r] = fmaxf(fmaxf(pmax[row], pmax[16 + row]), fmaxf(pmax[32 + row], pmax[48 + row]));
  }
  #pragma unroll
  for (int ct = 0; ct < 8; ++ct)
    #pragma unroll
    for (int r = 0; r < 4; ++r) {
      float p = __expf(acc[ct][r] - M[r]);
      acc[ct][r] = p;
      sm[r] += p;
    }
  #pragma unroll
  for (int o = 1; o < 16; o <<= 1)
    #pragma unroll
    for (int r = 0; r < 4; ++r) sm[r] += __shfl_xor(sm[r], o);
  if (lr == 0) {
    #pragma unroll
    for (int r = 0; r < 4; ++r) psum[w * 16 + hi * 4 + r] = sm[r];
  }
  // ---- write P bf16 (swizzled) while sums settle
  char* Pb = (char*)P;
  #pragma unroll
  for (int ct = 0; ct < 8; ++ct) {
    int col = w * 128 + ct * 16 + lr;
    #pragma unroll
    for (int r = 0; r < 4; ++r) {
      int row = hi * 4 + r;
      int byte = (row * 1024 + col * 2) ^ ((row & 7) << 4);
      *(u16*)(Pb + byte) = f2bf(acc[ct][r]);
    }
  }
  __syncthreads();

  float rinv[4];
  #pragma unroll
  for (int r = 0; r < 4; ++r) {
    int row = hi * 4 + r;
    rinv[r] = 1.0f / (psum[row] + psum[16 + row] + psum[32 + row] + psum[48 + row]);
  }

  // ---- phase 3: out = P @ V (wave w owns output cols w*16..w*16+16)
  {
    const int n0 = w * 16;
    f32x4 oacc = (f32x4){0.f, 0.f, 0.f, 0.f};
    #pragma unroll
    for (int ks = 0; ks < 16; ++ks) {
      int byte = (lr * 1024 + (ks * 32 + lk) * 2) ^ ((lr & 7) << 4);
      bfx8 pa = *(const bfx8*)(Pb + byte);
      bfx8 vf = *(const bfx8*)(vT + ((size_t)bh * DK_ + n0 + lr) * T_ + ks * 32 + lk);
      oacc = __builtin_amdgcn_mfma_f32_16x16x32_bf16(pa, vf, oacc, 0, 0, 0);
    }
    #pragma unroll
    for (int r = 0; r < 4; ++r) {
      int i = i0 + hi * 4 + r;
      ao[((size_t)b * T_ + i) * D_ + h * DK_ + n0 + lr] = f2bf(oacc[r] * rinv[r]);
    }
  }
}

extern "C" void kernel_launch(void* const* d_in, const int* in_sizes, int n_in,
                              void* d_out, int out_size, void* d_ws, size_t ws_size,
                              hipStream_t stream) {
  (void)in_sizes; (void)n_in; (void)out_size; (void)ws_size;
  const float* x    = (const float*)d_in[0];
  const float* tmat = (const float*)d_in[1];
  const int*   pad  = (const int*)d_in[2];
  const float* wq = (const float*)d_in[3];  const float* bq = (const float*)d_in[4];
  const float* wk = (const float*)d_in[5];  const float* bk = (const float*)d_in[6];
  const float* wv = (const float*)d_in[7];  const float* bv = (const float*)d_in[8];
  const float* wp = (const float*)d_in[9];  const float* bp = (const float*)d_in[10];
  const float* tb1w = (const float*)d_in[11]; const float* tb1b = (const float*)d_in[12];
  const float* tb2w = (const float*)d_in[13]; const float* tb2b = (const float*)d_in[14];
  const float* fc1w = (const float*)d_in[15]; const float* fc1b = (const float*)d_in[16];
  const float* fc2w = (const float*)d_in[17]; const float* fc2b = (const float*)d_in[18];
  const float* ln1g = (const float*)d_in[19]; const float* ln1b = (const float*)d_in[20];
  const float* ln2g = (const float*)d_in[21]; const float* ln2b = (const float*)d_in[22];
  float* out = (float*)d_out;

  // ---- workspace layout (with aliasing of dead buffers onto split-K partials)
  char* p = (char*)d_ws;
  u16* wqT  = (u16*)p; p += (size_t)768 * 768 * 2;
  u16* wkT  = (u16*)p; p += (size_t)768 * 768 * 2;
  u16* wvT  = (u16*)p; p += (size_t)768 * 768 * 2;
  u16* wpT  = (u16*)p; p += (size_t)768 * 768 * 2;
  u16* fc1T = (u16*)p; p += (size_t)768 * 3072 * 2;
  u16* fc2T = (u16*)p; p += (size_t)3072 * 768 * 2;
  float* x1 = (float*)p; p += (size_t)NTOK * D_ * 4;
  u16* gbuf = (u16*)p; p += (size_t)NTOK * FF_ * 2;
  char* pool = p;   // 25165824-byte overlay pool
  u16*   hbuf  = (u16*)(pool + 0);
  u16*   qb    = (u16*)(pool + 3145728);
  u16*   kb    = (u16*)(pool + 6291456);
  u16*   vTb   = (u16*)(pool + 9437184);
  float* biasM = (float*)(pool + 12582912);
  u16*   ao    = (u16*)(pool + 16777216);
  u16*   h2    = (u16*)(pool + 19922944);
  float* partP = (float*)(pool + 0);   // proj split-2 partials (12.6 MB) — qb/kb/vTb/hbuf dead
  float* partF = (float*)(pool + 0);   // ffn2 split-4 partials (25.2 MB) — whole pool dead

  dim3 tpb(32, 8);
  transpose_cast<<<dim3(24, 24), tpb, 0, stream>>>(wq, wqT, 768, 768);
  transpose_cast<<<dim3(24, 24), tpb, 0, stream>>>(wk, wkT, 768, 768);
  transpose_cast<<<dim3(24, 24), tpb, 0, stream>>>(wv, wvT, 768, 768);
  transpose_cast<<<dim3(24, 24), tpb, 0, stream>>>(wp, wpT, 768, 768);
  transpose_cast<<<dim3(96, 24), tpb, 0, stream>>>(fc1w, fc1T, 768, 3072);
  transpose_cast<<<dim3(24, 96), tpb, 0, stream>>>(fc2w, fc2T, 3072, 768);

  ln_cast<<<NTOK, 256, 0, stream>>>(x, ln1g, ln1b, hbuf);
  bias_mlp<<<(B_ * T_ * T_) / 256, 256, 0, stream>>>(tmat, pad, tb1w, tb1b, tb2w, tb2b, biasM);

  gemm_qkv<<<dim3(6, 16, 3), 256, 0, stream>>>(hbuf, wqT, wkT, wvT, bq, bk, bv, qb, kb, vTb);
  attn_kernel<<<1536, 256, 0, stream>>>(qb, kb, vTb, biasM, ao);

  // proj: split-K=2 (192 blocks), then reduce fused with LN2
  gemm_part<<<dim3(6, 16, 2), 256, 0, stream>>>(ao, wpT, partP, NTOK, 768, 768, 384);
  reduce_ln<<<NTOK, 256, 0, stream>>>(partP, x, bp, ln2g, ln2b, x1, h2);

  // FFN1 (384 blocks)
  gemm_gelu<<<dim3(24, 16), 256, 0, stream>>>(h2, fc1T, fc1b, gbuf, NTOK, FF_, 768);

  // FFN2: split-K=4 (384 blocks), then reduce + residual
  gemm_part<<<dim3(6, 16, 4), 256, 0, stream>>>(gbuf, fc2T, partF, NTOK, 768, 3072, 768);
  reduce_out<<<NTOK * D_ / 4 / 256, 256, 0, stream>>>(partF, x1, fc2b, out);
}

// Round 4
// 153.067 us; speedup vs baseline: 1.5090x; 1.1444x over previous
//
#include <hip/hip_runtime.h>
#include <hip/hip_bf16.h>
#include <math.h>

#define B_ 4
#define T_ 512
#define D_ 768
#define H_ 12
#define FF_ 3072
#define DK_ 64
#define NTOK (B_*T_)
#define NEGV -1e9f

typedef unsigned short u16;
typedef __bf16 bfx8 __attribute__((ext_vector_type(8)));
typedef float f32x4 __attribute__((ext_vector_type(4)));
typedef u16 u16x8 __attribute__((ext_vector_type(8)));

__device__ __forceinline__ u16 f2bf(float f) {
  union { float f; unsigned u; } v; v.f = f;
  unsigned r = (v.u + 0x7FFFu + ((v.u >> 16) & 1u)) >> 16;   // RNE
  return (u16)r;
}

__device__ __forceinline__ void glds16(const u16* g, u16* l) {
  __builtin_amdgcn_global_load_lds((const __attribute__((address_space(1))) void*)g,
                                   (__attribute__((address_space(3))) void*)l, 16, 0, 0);
}

// ---------------- fused weight transpose + cast (all 6 weights, one dispatch)
// in (K,N) f32 -> out (N,K) bf16
__global__ void transpose_all(const float* __restrict__ wq, const float* __restrict__ wk,
                              const float* __restrict__ wv, const float* __restrict__ wp,
                              const float* __restrict__ fc1, const float* __restrict__ fc2,
                              u16* wqT, u16* wkT, u16* wvT, u16* wpT, u16* fc1T, u16* fc2T)
{
  __shared__ float tile[32][33];
  const int bid = blockIdx.x;
  const float* in; u16* outp; int K, N, local;
  if (bid < 2304) {                        // 4 square weights, 576 tiles each
    int m = bid / 576; local = bid % 576; K = 768; N = 768;
    in   = m == 0 ? wq  : (m == 1 ? wk  : (m == 2 ? wv  : wp));
    outp = m == 0 ? wqT : (m == 1 ? wkT : (m == 2 ? wvT : wpT));
  } else if (bid < 4608) {
    local = bid - 2304; K = 768; N = 3072; in = fc1; outp = fc1T;
  } else {
    local = bid - 4608; K = 3072; N = 768; in = fc2; outp = fc2T;
  }
  const int nt = N / 32;
  const int n0 = (local % nt) * 32, k0 = (local / nt) * 32;
  const int tx = threadIdx.x, ty = threadIdx.y;   // (32,8)
  #pragma unroll
  for (int i = 0; i < 4; ++i) {
    int r = ty + i * 8;
    tile[r][tx] = in[(size_t)(k0 + r) * N + n0 + tx];
  }
  __syncthreads();
  #pragma unroll
  for (int i = 0; i < 4; ++i) {
    int r = ty + i * 8;
    outp[(size_t)(n0 + r) * K + k0 + tx] = f2bf(tile[tx][r]);
  }
}

// ---------------- LayerNorm (row = 768) -> bf16 (LN1)
__global__ __launch_bounds__(256) void ln_cast(const float* __restrict__ x, const float* __restrict__ g,
                                               const float* __restrict__ b, u16* __restrict__ out)
{
  const int row = blockIdx.x;
  const int tid = threadIdx.x;
  const float* xr = x + (size_t)row * D_;
  float v0 = xr[tid], v1 = xr[tid + 256], v2 = xr[tid + 512];
  float s = v0 + v1 + v2;
  float sq = v0 * v0 + v1 * v1 + v2 * v2;
  #pragma unroll
  for (int o = 32; o > 0; o >>= 1) { s += __shfl_down(s, o); sq += __shfl_down(sq, o); }
  __shared__ float ss[4], s2[4];
  int w = tid >> 6;
  if ((tid & 63) == 0) { ss[w] = s; s2[w] = sq; }
  __syncthreads();
  s = ss[0] + ss[1] + ss[2] + ss[3];
  sq = s2[0] + s2[1] + s2[2] + s2[3];
  float mean = s * (1.0f / 768.0f);
  float inv = rsqrtf(sq * (1.0f / 768.0f) - mean * mean + 1e-5f);
  u16* orow = out + (size_t)row * D_;
  orow[tid]       = f2bf((v0 - mean) * inv * g[tid]       + b[tid]);
  orow[tid + 256] = f2bf((v1 - mean) * inv * g[tid + 256] + b[tid + 256]);
  orow[tid + 512] = f2bf((v2 - mean) * inv * g[tid + 512] + b[tid + 512]);
}

// ---------------- temporal bias MLP (+ padding mask), per (b,i,j), fp32
__global__ __launch_bounds__(256) void bias_mlp(const float* __restrict__ tmat, const int* __restrict__ pad,
    const float* __restrict__ w1, const float* __restrict__ b1,
    const float* __restrict__ w2, const float* __restrict__ b2,
    float* __restrict__ biasM)
{
  __shared__ float sw1[64], sb1[64], sw2[64];
  if (threadIdx.x < 64) {
    sw1[threadIdx.x] = w1[threadIdx.x];
    sb1[threadIdx.x] = b1[threadIdx.x];
    sw2[threadIdx.x] = w2[threadIdx.x];
  }
  __syncthreads();
  size_t idx = (size_t)blockIdx.x * 256 + threadIdx.x;   // over B*T*T
  float tm = 1.0f / __logf(2.718281828459045f + tmat[idx]);
  float acc = b2[0];
  #pragma unroll
  for (int t = 0; t < 64; ++t) {
    float u = fmaf(tm, sw1[t], sb1[t]);
    u = u > 0.0f ? u : 0.2f * u;          // leaky_relu(0.2)
    acc = fmaf(u, sw2[t], acc);
  }
  biasM[idx] = (pad[idx] == 0) ? NEGV : acc;   // (B,1,T,T): same flat index
}

// ---------------- 2-phase double-buffered GEMM mainloop (T3-min recipe)
// C(M,N) = A(M,K) * BT(N,K)^T over k in [k0, k0+32*nk), 128x128 tile
// As/Bs are 2*4096 u16 (double-buffered)
__device__ __forceinline__ void gemm_tile_db(
    const u16* __restrict__ A, const u16* __restrict__ BT,
    int K, int nk, int m0, int n0, int k0,
    u16* As, u16* Bs, f32x4 acc[4][4])
{
  const int tid = threadIdx.x;
  const int w = tid >> 6, lane = tid & 63;
  const int lr = lane & 15, lk = (lane >> 4) * 8;
  const int wm = (w >> 1) * 64, wn = (w & 1) * 64;
  const int c0 = w * 64 + lane, c1 = 256 + c0;
  const int r0 = c0 >> 2, o0 = (c0 & 3) * 8;
  const int r1 = c1 >> 2, o1 = (c1 & 3) * 8;
  const u16* ga0 = A  + (size_t)(m0 + r0) * K + k0 + o0;
  const u16* ga1 = A  + (size_t)(m0 + r1) * K + k0 + o1;
  const u16* gb0 = BT + (size_t)(n0 + r0) * K + k0 + o0;
  const u16* gb1 = BT + (size_t)(n0 + r1) * K + k0 + o1;
  u16* la0 = As + w * 512;           // wave-uniform LDS bases (lane*16B added by HW)
  u16* la1 = As + 2048 + w * 512;
  u16* lb0 = Bs + w * 512;
  u16* lb1 = Bs + 2048 + w * 512;
  // prologue: stage tile 0 into buf 0
  glds16(ga0, la0); glds16(ga1, la1); glds16(gb0, lb0); glds16(gb1, lb1);
  __syncthreads();
  int cur = 0;
  for (int kt = 0; kt < nk; ++kt) {
    const int nxt = cur ^ 1;
    if (kt + 1 < nk) {                 // issue next tile's loads BEFORE compute
      ga0 += 32; ga1 += 32; gb0 += 32; gb1 += 32;
      glds16(ga0, la0 + nxt * 4096); glds16(ga1, la1 + nxt * 4096);
      glds16(gb0, lb0 + nxt * 4096); glds16(gb1, lb1 + nxt * 4096);
    }
    const u16* Asc = As + cur * 4096;
    const u16* Bsc = Bs + cur * 4096;
    bfx8 af[4], bfr[4];
    #pragma unroll
    for (int t = 0; t < 4; ++t) {
      af[t]  = *(const bfx8*)&Asc[(wm + t * 16 + lr) * 32 + lk];
      bfr[t] = *(const bfx8*)&Bsc[(wn + t * 16 + lr) * 32 + lk];
    }
    #pragma unroll
    for (int rt = 0; rt < 4; ++rt)
      #pragma unroll
      for (int ct = 0; ct < 4; ++ct)
        acc[rt][ct] = __builtin_amdgcn_mfma_f32_16x16x32_bf16(af[rt], bfr[ct], acc[rt][ct], 0, 0, 0);
    __syncthreads();                   // one drain+barrier per tile
    cur = nxt;
  }
}

// QKV fused over blockIdx.z (0=q,1=k,2=v)
__global__ __launch_bounds__(256) void gemm_qkv(
    const u16* __restrict__ A,
    const u16* __restrict__ wqT, const u16* __restrict__ wkT, const u16* __restrict__ wvT,
    const float* __restrict__ bq, const float* __restrict__ bk, const float* __restrict__ bv,
    u16* __restrict__ qo, u16* __restrict__ ko, u16* __restrict__ vo)
{
  __shared__ u16 As[2 * 128 * 32];
  __shared__ u16 Bs[2 * 128 * 32];
  const int z = blockIdx.z;
  const u16* BT = z == 0 ? wqT : (z == 1 ? wkT : wvT);
  const float* bias = z == 0 ? bq : (z == 1 ? bk : bv);
  u16* outp = z == 0 ? qo : (z == 1 ? ko : vo);
  const float scale = z == 0 ? 0.125f : 1.0f;   // DK^-0.5 folded into q
  const int m0 = blockIdx.y * 128, n0 = blockIdx.x * 128;
  f32x4 acc[4][4];
  #pragma unroll
  for (int a = 0; a < 4; ++a)
    #pragma unroll
    for (int bb = 0; bb < 4; ++bb) acc[a][bb] = (f32x4){0.f, 0.f, 0.f, 0.f};
  gemm_tile_db(A, BT, D_, D_ / 32, m0, n0, 0, As, Bs, acc);
  const int tid = threadIdx.x;
  const int w = tid >> 6, lane = tid & 63;
  const int lr = lane & 15;
  const int wm = (w >> 1) * 64, wn = (w & 1) * 64;
  #pragma unroll
  for (int rt = 0; rt < 4; ++rt)
    #pragma unroll
    for (int ct = 0; ct < 4; ++ct)
      #pragma unroll
      for (int r = 0; r < 4; ++r) {
        int m = m0 + wm + rt * 16 + (lane >> 4) * 4 + r;
        int n = n0 + wn + ct * 16 + lr;
        float val = (acc[rt][ct][r] + bias[n]) * scale;
        int b = m >> 9, t = m & 511, hh = n >> 6, d = n & 63;
        if (z < 2) outp[(((size_t)b * H_ + hh) * T_ + t) * DK_ + d] = f2bf(val);
        else       outp[(((size_t)b * H_ + hh) * DK_ + d) * T_ + t] = f2bf(val);
      }
}

// split-K GEMM -> fp32 partials part[kz][M][N]
__global__ __launch_bounds__(256) void gemm_part(
    const u16* __restrict__ A, const u16* __restrict__ BT,
    float* __restrict__ part, int M, int N, int K, int Ksplit)
{
  __shared__ u16 As[2 * 128 * 32];
  __shared__ u16 Bs[2 * 128 * 32];
  const int m0 = blockIdx.y * 128, n0 = blockIdx.x * 128;
  const int kz = blockIdx.z;
  f32x4 acc[4][4];
  #pragma unroll
  for (int a = 0; a < 4; ++a)
    #pragma unroll
    for (int bb = 0; bb < 4; ++bb) acc[a][bb] = (f32x4){0.f, 0.f, 0.f, 0.f};
  gemm_tile_db(A, BT, K, Ksplit / 32, m0, n0, kz * Ksplit, As, Bs, acc);
  const int tid = threadIdx.x;
  const int w = tid >> 6, lane = tid & 63;
  const int lr = lane & 15;
  const int wm = (w >> 1) * 64, wn = (w & 1) * 64;
  float* pp = part + (size_t)kz * M * N;
  #pragma unroll
  for (int rt = 0; rt < 4; ++rt)
    #pragma unroll
    for (int ct = 0; ct < 4; ++ct)
      #pragma unroll
      for (int r = 0; r < 4; ++r) {
        int m = m0 + wm + rt * 16 + (lane >> 4) * 4 + r;
        int n = n0 + wn + ct * 16 + lr;
        pp[(size_t)m * N + n] = acc[rt][ct][r];
      }
}

// FFN1: gelu epilogue -> bf16
__global__ __launch_bounds__(256) void gemm_gelu(
    const u16* __restrict__ A, const u16* __restrict__ BT,
    const float* __restrict__ bias, u16* __restrict__ outp, int M, int N, int K)
{
  __shared__ u16 As[2 * 128 * 32];
  __shared__ u16 Bs[2 * 128 * 32];
  const int m0 = blockIdx.y * 128, n0 = blockIdx.x * 128;
  f32x4 acc[4][4];
  #pragma unroll
  for (int a = 0; a < 4; ++a)
    #pragma unroll
    for (int bb = 0; bb < 4; ++bb) acc[a][bb] = (f32x4){0.f, 0.f, 0.f, 0.f};
  gemm_tile_db(A, BT, K, K / 32, m0, n0, 0, As, Bs, acc);
  const int tid = threadIdx.x;
  const int w = tid >> 6, lane = tid & 63;
  const int lr = lane & 15;
  const int wm = (w >> 1) * 64, wn = (w & 1) * 64;
  #pragma unroll
  for (int rt = 0; rt < 4; ++rt)
    #pragma unroll
    for (int ct = 0; ct < 4; ++ct)
      #pragma unroll
      for (int r = 0; r < 4; ++r) {
        int m = m0 + wm + rt * 16 + (lane >> 4) * 4 + r;
        int n = n0 + wn + ct * 16 + lr;
        float val = acc[rt][ct][r] + bias[n];
        float gl = 0.5f * val * (1.0f + erff(val * 0.7071067811865475f));
        outp[(size_t)m * N + n] = f2bf(gl);
      }
}

// proj reduce (2 partials) + residual + bias, then fused LN2 -> x1 (f32) + h2 (bf16)
__global__ __launch_bounds__(256) void reduce_ln(
    const float* __restrict__ part, const float* __restrict__ x, const float* __restrict__ bp,
    const float* __restrict__ g, const float* __restrict__ bta,
    float* __restrict__ x1, u16* __restrict__ h2)
{
  const int row = blockIdx.x;
  const int tid = threadIdx.x;
  const size_t base = (size_t)row * D_;
  const size_t slab = (size_t)NTOK * D_;
  float v[3];
  float s = 0.f, sq = 0.f;
  #pragma unroll
  for (int i = 0; i < 3; ++i) {
    int c = tid + i * 256;
    float val = x[base + c] + bp[c] + part[base + c] + part[slab + base + c];
    v[i] = val;
    s += val; sq += val * val;
  }
  #pragma unroll
  for (int o = 32; o > 0; o >>= 1) { s += __shfl_down(s, o); sq += __shfl_down(sq, o); }
  __shared__ float ss[4], s2[4];
  int w = tid >> 6;
  if ((tid & 63) == 0) { ss[w] = s; s2[w] = sq; }
  __syncthreads();
  s = ss[0] + ss[1] + ss[2] + ss[3];
  sq = s2[0] + s2[1] + s2[2] + s2[3];
  float mean = s * (1.0f / 768.0f);
  float inv = rsqrtf(sq * (1.0f / 768.0f) - mean * mean + 1e-5f);
  #pragma unroll
  for (int i = 0; i < 3; ++i) {
    int c = tid + i * 256;
    x1[base + c] = v[i];
    h2[base + c] = f2bf((v[i] - mean) * inv * g[c] + bta[c]);
  }
}

// FFN2 reduce (4 partials) + residual + bias -> out f32, float4-vectorized
__global__ __launch_bounds__(256) void reduce_out(
    const float* __restrict__ part, const float* __restrict__ x1,
    const float* __restrict__ bias, float* __restrict__ out)
{
  const size_t i = (size_t)blockIdx.x * 256 + threadIdx.x;   // over NTOK*D/4
  const size_t slab = (size_t)NTOK * D_ / 4;
  float4 b = ((const float4*)bias)[i % (D_ / 4)];
  float4 a = ((const float4*)x1)[i];
  float4 p0 = ((const float4*)part)[i];
  float4 p1 = ((const float4*)part)[i + slab];
  float4 p2 = ((const float4*)part)[i + 2 * slab];
  float4 p3 = ((const float4*)part)[i + 3 * slab];
  float4 o;
  o.x = a.x + b.x + p0.x + p1.x + p2.x + p3.x;
  o.y = a.y + b.y + p0.y + p1.y + p2.y + p3.y;
  o.z = a.z + b.z + p0.z + p1.z + p2.z + p3.z;
  o.w = a.w + b.w + p0.w + p1.w + p2.w + p3.w;
  ((float4*)out)[i] = o;
}

// ---------------- attention v3: causal column skipping + scores in registers
// column-tile t (16 cols) owned by wave t%4; only t <= tmax computed.
// 1-D grid, XCD-chunked: 6 bh per XCD so K/V/bias slice stays in its L2
__global__ __launch_bounds__(256) void attn_kernel(
    const u16* __restrict__ q, const u16* __restrict__ k, const u16* __restrict__ vT,
    const float* __restrict__ biasM, u16* __restrict__ ao)
{
  __shared__ u16 P[16 * 512];           // unnormalized bf16 P, XOR-swizzled
  __shared__ float pmax[64], psum[64];  // [wave][row]
  const int tid = threadIdx.x;
  const int w = tid >> 6, lane = tid & 63;
  const int lr = lane & 15, hi = lane >> 4, lk = hi * 8;

  const int bid = blockIdx.x;
  const int xcd = bid & 7, idx = bid >> 3;     // 192 blocks per XCD
  const int bh = xcd * 6 + (idx >> 5);         // 6 bh per XCD
  const int i0 = (idx & 31) * 16;
  const int b = bh / H_, h = bh % H_;
  // causal work bounds: block i0>0 needs cols <= i0+15 (block 0: row 0 sees all)
  const int tmax = (i0 == 0) ? 31 : ((i0 >> 4) + 1);   // 16-col tiles (rounded to cover PV reads)
  const int nks  = (i0 == 0) ? 16 : ((i0 >> 5) + 1);   // 32-col PV k-tiles

  // ---- phase 1: scores in registers. acc[ct][r] = S[row=hi*4+r][col=(ct*4+w)*16+lr]
  bfx8 qf[2];
  #pragma unroll
  for (int ks = 0; ks < 2; ++ks)
    qf[ks] = *(const bfx8*)(q + ((size_t)bh * T_ + i0 + lr) * DK_ + ks * 32 + lk);
  f32x4 acc[8];
  float mx[4] = {-3.4e38f, -3.4e38f, -3.4e38f, -3.4e38f};
  #pragma unroll
  for (int ct = 0; ct < 8; ++ct) {
    const int t = ct * 4 + w;
    if (t > tmax) continue;             // wave-uniform skip
    const int j0 = t * 16;
    bfx8 kf0 = *(const bfx8*)(k + ((size_t)bh * T_ + j0 + lr) * DK_ + lk);
    bfx8 kf1 = *(const bfx8*)(k + ((size_t)bh * T_ + j0 + lr) * DK_ + 32 + lk);
    f32x4 a0 = (f32x4){0.f, 0.f, 0.f, 0.f};
    a0 = __builtin_amdgcn_mfma_f32_16x16x32_bf16(qf[0], kf0, a0, 0, 0, 0);
    a0 = __builtin_amdgcn_mfma_f32_16x16x32_bf16(qf[1], kf1, a0, 0, 0, 0);
    const int j = j0 + lr;
    #pragma unroll
    for (int r = 0; r < 4; ++r) {
      int i = i0 + hi * 4 + r;
      float s = a0[r] + biasM[((size_t)b * T_ + i) * T_ + j];
      if (j > i && i != 0) s = NEGV;    // causal; CLS row 0 fully visible
      a0[r] = s;
      mx[r] = fmaxf(mx[r], s);
    }
    acc[ct] = a0;
  }
  #pragma unroll
  for (int o = 1; o < 16; o <<= 1)
    #pragma unroll
    for (int r = 0; r < 4; ++r) mx[r] = fmaxf(mx[r], __shfl_xor(mx[r], o));
  if (lr == 0) {
    #pragma unroll
    for (int r = 0; r < 4; ++r) pmax[w * 16 + hi * 4 + r] = mx[r];
  }
  __syncthreads();

  // ---- exp (unnormalized) + per-row sum
  float sm[4] = {0.f, 0.f, 0.f, 0.f};
  float M[4];
  #pragma unroll
  for (int r = 0; r < 4; ++r) {
    int row = hi * 4 + r;
    M[r] = fmaxf(fmaxf(pmax[row], pmax[16 + row]), fmaxf(pmax[32 + row], pmax[48 + row]));
  }
  char* Pb = (char*)P;
  #pragma unroll
  for (int ct = 0; ct < 8; ++ct) {
    const int t = ct * 4 + w;
    if (t > tmax) continue;
    const int col = t * 16 + lr;
    #pragma unroll
    for (int r = 0; r < 4; ++r) {
      float p = __expf(acc[ct][r] - M[r]);
      sm[r] += p;
      int row = hi * 4 + r;
      int byte = (row * 1024 + col * 2) ^ ((row & 7) << 4);
      *(u16*)(Pb + byte) = f2bf(p);
    }
  }
  #pragma unroll
  for (int o = 1; o < 16; o <<= 1)
    #pragma unroll
    for (int r = 0; r < 4; ++r) sm[r] += __shfl_xor(sm[r], o);
  if (lr == 0) {
    #pragma unroll
    for (int r = 0; r < 4; ++r) psum[w * 16 + hi * 4 + r] = sm[r];
  }
  __syncthreads();

  float rinv[4];
  #pragma unroll
  for (int r = 0; r < 4; ++r) {
    int row = hi * 4 + r;
    rinv[r] = 1.0f / (psum[row] + psum[16 + row] + psum[32 + row] + psum[48 + row]);
  }

  // ---- phase 3: out = P @ V (wave w owns output cols w*16..w*16+16)
  {
    const int n0 = w * 16;
    f32x4 oacc = (f32x4){0.f, 0.f, 0.f, 0.f};
    for (int ks = 0; ks < nks; ++ks) {
      int byte = (lr * 1024 + (ks * 32 + lk) * 2) ^ ((lr & 7) << 4);
      bfx8 pa = *(const bfx8*)(Pb + byte);
      bfx8 vf = *(const bfx8*)(vT + ((size_t)bh * DK_ + n0 + lr) * T_ + ks * 32 + lk);
      oacc = __builtin_amdgcn_mfma_f32_16x16x32_bf16(pa, vf, oacc, 0, 0, 0);
    }
    #pragma unroll
    for (int r = 0; r < 4; ++r) {
      int i = i0 + hi * 4 + r;
      ao[((size_t)b * T_ + i) * D_ + h * DK_ + n0 + lr] = f2bf(oacc[r] * rinv[r]);
    }
  }
}

extern "C" void kernel_launch(void* const* d_in, const int* in_sizes, int n_in,
                              void* d_out, int out_size, void* d_ws, size_t ws_size,
                              hipStream_t stream) {
  (void)in_sizes; (void)n_in; (void)out_size; (void)ws_size;
  const float* x    = (const float*)d_in[0];
  const float* tmat = (const float*)d_in[1];
  const int*   pad  = (const int*)d_in[2];
  const float* wq = (const float*)d_in[3];  const float* bq = (const float*)d_in[4];
  const float* wk = (const float*)d_in[5];  const float* bk = (const float*)d_in[6];
  const float* wv = (const float*)d_in[7];  const float* bv = (const float*)d_in[8];
  const float* wp = (const float*)d_in[9];  const float* bp = (const float*)d_in[10];
  const float* tb1w = (const float*)d_in[11]; const float* tb1b = (const float*)d_in[12];
  const float* tb2w = (const float*)d_in[13]; const float* tb2b = (const float*)d_in[14];
  const float* fc1w = (const float*)d_in[15]; const float* fc1b = (const float*)d_in[16];
  const float* fc2w = (const float*)d_in[17]; const float* fc2b = (const float*)d_in[18];
  const float* ln1g = (const float*)d_in[19]; const float* ln1b = (const float*)d_in[20];
  const float* ln2g = (const float*)d_in[21]; const float* ln2b = (const float*)d_in[22];
  float* out = (float*)d_out;

  // ---- workspace layout (with aliasing of dead buffers onto split-K partials)
  char* p = (char*)d_ws;
  u16* wqT  = (u16*)p; p += (size_t)768 * 768 * 2;
  u16* wkT  = (u16*)p; p += (size_t)768 * 768 * 2;
  u16* wvT  = (u16*)p; p += (size_t)768 * 768 * 2;
  u16* wpT  = (u16*)p; p += (size_t)768 * 768 * 2;
  u16* fc1T = (u16*)p; p += (size_t)768 * 3072 * 2;
  u16* fc2T = (u16*)p; p += (size_t)3072 * 768 * 2;
  float* x1 = (float*)p; p += (size_t)NTOK * D_ * 4;
  u16* gbuf = (u16*)p; p += (size_t)NTOK * FF_ * 2;
  char* pool = p;   // 25165824-byte overlay pool
  u16*   hbuf  = (u16*)(pool + 0);
  u16*   qb    = (u16*)(pool + 3145728);
  u16*   kb    = (u16*)(pool + 6291456);
  u16*   vTb   = (u16*)(pool + 9437184);
  float* biasM = (float*)(pool + 12582912);
  u16*   ao    = (u16*)(pool + 16777216);
  u16*   h2    = (u16*)(pool + 19922944);
  float* partP = (float*)(pool + 0);   // proj split-2 partials (12.6 MB) — qb/kb/vTb/hbuf dead
  float* partF = (float*)(pool + 0);   // ffn2 split-4 partials (25.2 MB) — whole pool dead

  transpose_all<<<6912, dim3(32, 8), 0, stream>>>(wq, wk, wv, wp, fc1w, fc2w,
                                                  wqT, wkT, wvT, wpT, fc1T, fc2T);
  ln_cast<<<NTOK, 256, 0, stream>>>(x, ln1g, ln1b, hbuf);
  bias_mlp<<<(B_ * T_ * T_) / 256, 256, 0, stream>>>(tmat, pad, tb1w, tb1b, tb2w, tb2b, biasM);

  gemm_qkv<<<dim3(6, 16, 3), 256, 0, stream>>>(hbuf, wqT, wkT, wvT, bq, bk, bv, qb, kb, vTb);
  attn_kernel<<<1536, 256, 0, stream>>>(qb, kb, vTb, biasM, ao);

  // proj: split-K=2 (192 blocks), then reduce fused with LN2
  gemm_part<<<dim3(6, 16, 2), 256, 0, stream>>>(ao, wpT, partP, NTOK, 768, 768, 384);
  reduce_ln<<<NTOK, 256, 0, stream>>>(partP, x, bp, ln2g, ln2b, x1, h2);

  // FFN1 (384 blocks)
  gemm_gelu<<<dim3(24, 16), 256, 0, stream>>>(h2, fc1T, fc1b, gbuf, NTOK, FF_, 768);

  // FFN2: split-K=4 (384 blocks), then reduce + residual
  gemm_part<<<dim3(6, 16, 4), 256, 0, stream>>>(gbuf, fc2T, partF, NTOK, 768, 3072, 768);
  reduce_out<<<NTOK * D_ / 4 / 256, 256, 0, stream>>>(partF, x1, fc2b, out);
}

// Round 5
// 139.422 us; speedup vs baseline: 1.6566x; 1.0979x over previous
//
#include <hip/hip_runtime.h>
#include <hip/hip_bf16.h>
#include <math.h>

#define B_ 4
#define T_ 512
#define D_ 768
#define H_ 12
#define FF_ 3072
#define DK_ 64
#define NTOK (B_*T_)
#define NEGV -1e9f

typedef unsigned short u16;
typedef __bf16 bfx8 __attribute__((ext_vector_type(8)));
typedef float f32x4 __attribute__((ext_vector_type(4)));
typedef u16 u16x8 __attribute__((ext_vector_type(8)));

__device__ __forceinline__ u16 f2bf(float f) {
  union { float f; unsigned u; } v; v.f = f;
  unsigned r = (v.u + 0x7FFFu + ((v.u >> 16) & 1u)) >> 16;   // RNE
  return (u16)r;
}

__device__ __forceinline__ void glds16(const u16* g, u16* l) {
  __builtin_amdgcn_global_load_lds((const __attribute__((address_space(1))) void*)g,
                                   (__attribute__((address_space(3))) void*)l, 16, 0, 0);
}

// ---------------- fused prep: weight transposes + LN1 + temporal-bias MLP
// blocks [0,6912): transpose-cast  (K,N) f32 -> (N,K) bf16
// blocks [6912,8960): LN1 over x -> hbuf bf16
// blocks [8960,13056): bias MLP -> biasM f32 (+ padding mask)
__global__ __launch_bounds__(256) void prep_kernel(
    const float* __restrict__ x,
    const float* __restrict__ wq, const float* __restrict__ wk,
    const float* __restrict__ wv, const float* __restrict__ wp,
    const float* __restrict__ fc1, const float* __restrict__ fc2,
    u16* wqT, u16* wkT, u16* wvT, u16* wpT, u16* fc1T, u16* fc2T,
    const float* __restrict__ ln1g, const float* __restrict__ ln1b, u16* __restrict__ hbuf,
    const float* __restrict__ tmat, const int* __restrict__ pad,
    const float* __restrict__ tb1w, const float* __restrict__ tb1b,
    const float* __restrict__ tb2w, const float* __restrict__ tb2b,
    float* __restrict__ biasM)
{
  const int bid = blockIdx.x;
  const int tid = threadIdx.x;
  if (bid < 6912) {
    // ---- weight transpose+cast
    __shared__ float tile[32][33];
    const float* in; u16* outp; int K, N, local;
    if (bid < 2304) {
      int m = bid / 576; local = bid % 576; K = 768; N = 768;
      in   = m == 0 ? wq  : (m == 1 ? wk  : (m == 2 ? wv  : wp));
      outp = m == 0 ? wqT : (m == 1 ? wkT : (m == 2 ? wvT : wpT));
    } else if (bid < 4608) {
      local = bid - 2304; K = 768; N = 3072; in = fc1; outp = fc1T;
    } else {
      local = bid - 4608; K = 3072; N = 768; in = fc2; outp = fc2T;
    }
    const int nt = N / 32;
    const int n0 = (local % nt) * 32, k0 = (local / nt) * 32;
    const int tx = tid & 31, ty = tid >> 5;   // (32,8)
    #pragma unroll
    for (int i = 0; i < 4; ++i) {
      int r = ty + i * 8;
      tile[r][tx] = in[(size_t)(k0 + r) * N + n0 + tx];
    }
    __syncthreads();
    #pragma unroll
    for (int i = 0; i < 4; ++i) {
      int r = ty + i * 8;
      outp[(size_t)(n0 + r) * K + k0 + tx] = f2bf(tile[tx][r]);
    }
  } else if (bid < 8960) {
    // ---- LN1
    const int row = bid - 6912;
    const float* xr = x + (size_t)row * D_;
    float v0 = xr[tid], v1 = xr[tid + 256], v2 = xr[tid + 512];
    float s = v0 + v1 + v2;
    float sq = v0 * v0 + v1 * v1 + v2 * v2;
    #pragma unroll
    for (int o = 32; o > 0; o >>= 1) { s += __shfl_down(s, o); sq += __shfl_down(sq, o); }
    __shared__ float ss[4], s2[4];
    int w = tid >> 6;
    if ((tid & 63) == 0) { ss[w] = s; s2[w] = sq; }
    __syncthreads();
    s = ss[0] + ss[1] + ss[2] + ss[3];
    sq = s2[0] + s2[1] + s2[2] + s2[3];
    float mean = s * (1.0f / 768.0f);
    float inv = rsqrtf(sq * (1.0f / 768.0f) - mean * mean + 1e-5f);
    u16* orow = hbuf + (size_t)row * D_;
    orow[tid]       = f2bf((v0 - mean) * inv * ln1g[tid]       + ln1b[tid]);
    orow[tid + 256] = f2bf((v1 - mean) * inv * ln1g[tid + 256] + ln1b[tid + 256]);
    orow[tid + 512] = f2bf((v2 - mean) * inv * ln1g[tid + 512] + ln1b[tid + 512]);
  } else {
    // ---- temporal bias MLP
    __shared__ float sw1[64], sb1[64], sw2[64];
    if (tid < 64) {
      sw1[tid] = tb1w[tid];
      sb1[tid] = tb1b[tid];
      sw2[tid] = tb2w[tid];
    }
    __syncthreads();
    size_t idx = (size_t)(bid - 8960) * 256 + tid;
    float tm = 1.0f / __logf(2.718281828459045f + tmat[idx]);
    float acc = tb2b[0];
    #pragma unroll
    for (int t = 0; t < 64; ++t) {
      float u = fmaf(tm, sw1[t], sb1[t]);
      u = u > 0.0f ? u : 0.2f * u;          // leaky_relu(0.2)
      acc = fmaf(u, sw2[t], acc);
    }
    biasM[idx] = (pad[idx] == 0) ? NEGV : acc;
  }
}

// ---------------- depth-2 pipelined GEMM mainloop (counted vmcnt, 3 LDS bufs)
// C(M,N) = A(M,K) * BT(N,K)^T over k in [k0, k0+32*nk), 128x128 tile
// As/Bs are 3*4096 u16 each
__device__ __forceinline__ void gemm_tile_p2(
    const u16* __restrict__ A, const u16* __restrict__ BT,
    int K, int nk, int m0, int n0, int k0,
    u16* As, u16* Bs, f32x4 acc[4][4])
{
  const int tid = threadIdx.x;
  const int w = tid >> 6, lane = tid & 63;
  const int lr = lane & 15, lk = (lane >> 4) * 8;
  const int wm = (w >> 1) * 64, wn = (w & 1) * 64;
  const int c0 = w * 64 + lane, c1 = 256 + c0;
  const int r0 = c0 >> 2, o0 = (c0 & 3) * 8;
  const int r1 = c1 >> 2, o1 = (c1 & 3) * 8;
  const u16* gA0 = A  + (size_t)(m0 + r0) * K + k0 + o0;
  const u16* gA1 = A  + (size_t)(m0 + r1) * K + k0 + o1;
  const u16* gB0 = BT + (size_t)(n0 + r0) * K + k0 + o0;
  const u16* gB1 = BT + (size_t)(n0 + r1) * K + k0 + o1;
  u16* la0 = As + w * 512;            // wave-uniform LDS bases (lane*16B added by HW)
  u16* la1 = As + 2048 + w * 512;
  u16* lb0 = Bs + w * 512;
  u16* lb1 = Bs + 2048 + w * 512;
#define ISSUE_TILE(kk, b) do { \
    glds16(gA0 + (size_t)(kk) * 32, la0 + (b) * 4096); \
    glds16(gA1 + (size_t)(kk) * 32, la1 + (b) * 4096); \
    glds16(gB0 + (size_t)(kk) * 32, lb0 + (b) * 4096); \
    glds16(gB1 + (size_t)(kk) * 32, lb1 + (b) * 4096); } while (0)
  ISSUE_TILE(0, 0);
  if (nk > 1) ISSUE_TILE(1, 1);
  int cb = 0;
  for (int kt = 0; kt < nk; ++kt) {
    // wait for tile kt's 4 loads (oldest); keep tile kt+1 in flight
    if (kt < nk - 2) asm volatile("s_waitcnt vmcnt(4)" ::: "memory");
    else             asm volatile("s_waitcnt vmcnt(0)" ::: "memory");
    __builtin_amdgcn_sched_barrier(0);
    __builtin_amdgcn_s_barrier();      // all waves' tile-kt LDS writes landed
    __builtin_amdgcn_sched_barrier(0);
    const u16* Asc = As + cb * 4096;
    const u16* Bsc = Bs + cb * 4096;
    bfx8 af[4], bfr[4];
    #pragma unroll
    for (int t = 0; t < 4; ++t) {
      af[t]  = *(const bfx8*)&Asc[(wm + t * 16 + lr) * 32 + lk];
      bfr[t] = *(const bfx8*)&Bsc[(wn + t * 16 + lr) * 32 + lk];
    }
    #pragma unroll
    for (int rt = 0; rt < 4; ++rt)
      #pragma unroll
      for (int ct = 0; ct < 4; ++ct)
        acc[rt][ct] = __builtin_amdgcn_mfma_f32_16x16x32_bf16(af[rt], bfr[ct], acc[rt][ct], 0, 0, 0);
    // issue tile kt+2 into buf (cb+2)%3 — its old readers all passed this iter's barrier
    if (kt + 2 < nk) {
      int nb = cb + 2; if (nb >= 3) nb -= 3;
      ISSUE_TILE(kt + 2, nb);
    }
    cb = cb + 1; if (cb >= 3) cb = 0;
  }
#undef ISSUE_TILE
}

// QKV fused over blockIdx.z (0=q,1=k,2=v)
__global__ __launch_bounds__(256) void gemm_qkv(
    const u16* __restrict__ A,
    const u16* __restrict__ wqT, const u16* __restrict__ wkT, const u16* __restrict__ wvT,
    const float* __restrict__ bq, const float* __restrict__ bk, const float* __restrict__ bv,
    u16* __restrict__ qo, u16* __restrict__ ko, u16* __restrict__ vo)
{
  __shared__ u16 As[3 * 128 * 32];
  __shared__ u16 Bs[3 * 128 * 32];
  const int z = blockIdx.z;
  const u16* BT = z == 0 ? wqT : (z == 1 ? wkT : wvT);
  const float* bias = z == 0 ? bq : (z == 1 ? bk : bv);
  u16* outp = z == 0 ? qo : (z == 1 ? ko : vo);
  const float scale = z == 0 ? 0.125f : 1.0f;   // DK^-0.5 folded into q
  const int m0 = blockIdx.y * 128, n0 = blockIdx.x * 128;
  f32x4 acc[4][4];
  #pragma unroll
  for (int a = 0; a < 4; ++a)
    #pragma unroll
    for (int bb = 0; bb < 4; ++bb) acc[a][bb] = (f32x4){0.f, 0.f, 0.f, 0.f};
  gemm_tile_p2(A, BT, D_, D_ / 32, m0, n0, 0, As, Bs, acc);
  const int tid = threadIdx.x;
  const int w = tid >> 6, lane = tid & 63;
  const int lr = lane & 15;
  const int wm = (w >> 1) * 64, wn = (w & 1) * 64;
  #pragma unroll
  for (int rt = 0; rt < 4; ++rt)
    #pragma unroll
    for (int ct = 0; ct < 4; ++ct)
      #pragma unroll
      for (int r = 0; r < 4; ++r) {
        int m = m0 + wm + rt * 16 + (lane >> 4) * 4 + r;
        int n = n0 + wn + ct * 16 + lr;
        float val = (acc[rt][ct][r] + bias[n]) * scale;
        int b = m >> 9, t = m & 511, hh = n >> 6, d = n & 63;
        if (z < 2) outp[(((size_t)b * H_ + hh) * T_ + t) * DK_ + d] = f2bf(val);
        else       outp[(((size_t)b * H_ + hh) * DK_ + d) * T_ + t] = f2bf(val);
      }
}

// split-K GEMM -> fp32 partials part[kz][M][N]
__global__ __launch_bounds__(256) void gemm_part(
    const u16* __restrict__ A, const u16* __restrict__ BT,
    float* __restrict__ part, int M, int N, int K, int Ksplit)
{
  __shared__ u16 As[3 * 128 * 32];
  __shared__ u16 Bs[3 * 128 * 32];
  const int m0 = blockIdx.y * 128, n0 = blockIdx.x * 128;
  const int kz = blockIdx.z;
  f32x4 acc[4][4];
  #pragma unroll
  for (int a = 0; a < 4; ++a)
    #pragma unroll
    for (int bb = 0; bb < 4; ++bb) acc[a][bb] = (f32x4){0.f, 0.f, 0.f, 0.f};
  gemm_tile_p2(A, BT, K, Ksplit / 32, m0, n0, kz * Ksplit, As, Bs, acc);
  const int tid = threadIdx.x;
  const int w = tid >> 6, lane = tid & 63;
  const int lr = lane & 15;
  const int wm = (w >> 1) * 64, wn = (w & 1) * 64;
  float* pp = part + (size_t)kz * M * N;
  #pragma unroll
  for (int rt = 0; rt < 4; ++rt)
    #pragma unroll
    for (int ct = 0; ct < 4; ++ct)
      #pragma unroll
      for (int r = 0; r < 4; ++r) {
        int m = m0 + wm + rt * 16 + (lane >> 4) * 4 + r;
        int n = n0 + wn + ct * 16 + lr;
        pp[(size_t)m * N + n] = acc[rt][ct][r];
      }
}

// FFN1: gelu epilogue -> bf16
__global__ __launch_bounds__(256) void gemm_gelu(
    const u16* __restrict__ A, const u16* __restrict__ BT,
    const float* __restrict__ bias, u16* __restrict__ outp, int M, int N, int K)
{
  __shared__ u16 As[3 * 128 * 32];
  __shared__ u16 Bs[3 * 128 * 32];
  const int m0 = blockIdx.y * 128, n0 = blockIdx.x * 128;
  f32x4 acc[4][4];
  #pragma unroll
  for (int a = 0; a < 4; ++a)
    #pragma unroll
    for (int bb = 0; bb < 4; ++bb) acc[a][bb] = (f32x4){0.f, 0.f, 0.f, 0.f};
  gemm_tile_p2(A, BT, K, K / 32, m0, n0, 0, As, Bs, acc);
  const int tid = threadIdx.x;
  const int w = tid >> 6, lane = tid & 63;
  const int lr = lane & 15;
  const int wm = (w >> 1) * 64, wn = (w & 1) * 64;
  #pragma unroll
  for (int rt = 0; rt < 4; ++rt)
    #pragma unroll
    for (int ct = 0; ct < 4; ++ct)
      #pragma unroll
      for (int r = 0; r < 4; ++r) {
        int m = m0 + wm + rt * 16 + (lane >> 4) * 4 + r;
        int n = n0 + wn + ct * 16 + lr;
        float val = acc[rt][ct][r] + bias[n];
        float gl = 0.5f * val * (1.0f + erff(val * 0.7071067811865475f));
        outp[(size_t)m * N + n] = f2bf(gl);
      }
}

// proj reduce (2 partials) + residual + bias, then fused LN2 -> x1 (f32) + h2 (bf16)
__global__ __launch_bounds__(256) void reduce_ln(
    const float* __restrict__ part, const float* __restrict__ x, const float* __restrict__ bp,
    const float* __restrict__ g, const float* __restrict__ bta,
    float* __restrict__ x1, u16* __restrict__ h2)
{
  const int row = blockIdx.x;
  const int tid = threadIdx.x;
  const size_t base = (size_t)row * D_;
  const size_t slab = (size_t)NTOK * D_;
  float v[3];
  float s = 0.f, sq = 0.f;
  #pragma unroll
  for (int i = 0; i < 3; ++i) {
    int c = tid + i * 256;
    float val = x[base + c] + bp[c] + part[base + c] + part[slab + base + c];
    v[i] = val;
    s += val; sq += val * val;
  }
  #pragma unroll
  for (int o = 32; o > 0; o >>= 1) { s += __shfl_down(s, o); sq += __shfl_down(sq, o); }
  __shared__ float ss[4], s2[4];
  int w = tid >> 6;
  if ((tid & 63) == 0) { ss[w] = s; s2[w] = sq; }
  __syncthreads();
  s = ss[0] + ss[1] + ss[2] + ss[3];
  sq = s2[0] + s2[1] + s2[2] + s2[3];
  float mean = s * (1.0f / 768.0f);
  float inv = rsqrtf(sq * (1.0f / 768.0f) - mean * mean + 1e-5f);
  #pragma unroll
  for (int i = 0; i < 3; ++i) {
    int c = tid + i * 256;
    x1[base + c] = v[i];
    h2[base + c] = f2bf((v[i] - mean) * inv * g[c] + bta[c]);
  }
}

// FFN2 reduce (4 partials) + residual + bias -> out f32, float4-vectorized
__global__ __launch_bounds__(256) void reduce_out(
    const float* __restrict__ part, const float* __restrict__ x1,
    const float* __restrict__ bias, float* __restrict__ out)
{
  const size_t i = (size_t)blockIdx.x * 256 + threadIdx.x;   // over NTOK*D/4
  const size_t slab = (size_t)NTOK * D_ / 4;
  float4 b = ((const float4*)bias)[i % (D_ / 4)];
  float4 a = ((const float4*)x1)[i];
  float4 p0 = ((const float4*)part)[i];
  float4 p1 = ((const float4*)part)[i + slab];
  float4 p2 = ((const float4*)part)[i + 2 * slab];
  float4 p3 = ((const float4*)part)[i + 3 * slab];
  float4 o;
  o.x = a.x + b.x + p0.x + p1.x + p2.x + p3.x;
  o.y = a.y + b.y + p0.y + p1.y + p2.y + p3.y;
  o.z = a.z + b.z + p0.z + p1.z + p2.z + p3.z;
  o.w = a.w + b.w + p0.w + p1.w + p2.w + p3.w;
  ((float4*)out)[i] = o;
}

// ---------------- attention v4: 32 q-rows per block, causal column skipping,
// scores in registers, P bf16 swizzled LDS, V-frags shared across row-groups.
// 1-D grid (768), XCD-chunked: 6 bh per XCD.
__global__ __launch_bounds__(256) void attn_kernel(
    const u16* __restrict__ q, const u16* __restrict__ k, const u16* __restrict__ vT,
    const float* __restrict__ biasM, u16* __restrict__ ao)
{
  __shared__ u16 P[32 * 512];            // unnormalized bf16 P, XOR-swizzled (32 KB)
  __shared__ float pmax[128], psum[128]; // [wave][row 0..31]
  const int tid = threadIdx.x;
  const int w = tid >> 6, lane = tid & 63;
  const int lr = lane & 15, hi = lane >> 4, lk = hi * 8;

  const int bid = blockIdx.x;
  const int xcd = bid & 7, idx = bid >> 3;     // 96 blocks per XCD
  const int bh = xcd * 6 + (idx >> 4);         // 6 bh per XCD
  const int i0 = (idx & 15) * 32;
  const int b = bh / H_, h = bh % H_;
  // causal work bounds (rows i0..i0+31): need cols <= i0+31; block 0 row 0 sees all
  const int tmax = (i0 == 0) ? 31 : ((i0 >> 4) + 1);   // 16-col tiles
  const int nks  = (i0 == 0) ? 16 : ((i0 >> 5) + 1);   // 32-col PV k-tiles

  // ---- phase 1: scores in regs. acc[ct][g][r] = S[row=g*16+hi*4+r][col=(ct*4+w)*16+lr]
  bfx8 qf[2][2];
  #pragma unroll
  for (int g = 0; g < 2; ++g)
    #pragma unroll
    for (int ks = 0; ks < 2; ++ks)
      qf[g][ks] = *(const bfx8*)(q + ((size_t)bh * T_ + i0 + g * 16 + lr) * DK_ + ks * 32 + lk);
  f32x4 acc[8][2];
  float mx[2][4];
  #pragma unroll
  for (int g = 0; g < 2; ++g)
    #pragma unroll
    for (int r = 0; r < 4; ++r) mx[g][r] = -3.4e38f;
  #pragma unroll
  for (int ct = 0; ct < 8; ++ct) {
    const int t = ct * 4 + w;
    if (t > tmax) continue;              // wave-uniform skip
    const int j0 = t * 16;
    bfx8 kf0 = *(const bfx8*)(k + ((size_t)bh * T_ + j0 + lr) * DK_ + lk);
    bfx8 kf1 = *(const bfx8*)(k + ((size_t)bh * T_ + j0 + lr) * DK_ + 32 + lk);
    const int j = j0 + lr;
    #pragma unroll
    for (int g = 0; g < 2; ++g) {
      f32x4 a0 = (f32x4){0.f, 0.f, 0.f, 0.f};
      a0 = __builtin_amdgcn_mfma_f32_16x16x32_bf16(qf[g][0], kf0, a0, 0, 0, 0);
      a0 = __builtin_amdgcn_mfma_f32_16x16x32_bf16(qf[g][1], kf1, a0, 0, 0, 0);
      #pragma unroll
      for (int r = 0; r < 4; ++r) {
        int i = i0 + g * 16 + hi * 4 + r;
        float s = a0[r] + biasM[((size_t)b * T_ + i) * T_ + j];
        if (j > i && i != 0) s = NEGV;   // causal; CLS row 0 fully visible
        a0[r] = s;
        mx[g][r] = fmaxf(mx[g][r], s);
      }
      acc[ct][g] = a0;
    }
  }
  #pragma unroll
  for (int o = 1; o < 16; o <<= 1)
    #pragma unroll
    for (int g = 0; g < 2; ++g)
      #pragma unroll
      for (int r = 0; r < 4; ++r) mx[g][r] = fmaxf(mx[g][r], __shfl_xor(mx[g][r], o));
  if (lr == 0) {
    #pragma unroll
    for (int g = 0; g < 2; ++g)
      #pragma unroll
      for (int r = 0; r < 4; ++r) pmax[w * 32 + g * 16 + hi * 4 + r] = mx[g][r];
  }
  __syncthreads();

  // ---- exp (unnormalized) + per-row sum; write P bf16 swizzled
  float M2[2][4], sm[2][4];
  #pragma unroll
  for (int g = 0; g < 2; ++g)
    #pragma unroll
    for (int r = 0; r < 4; ++r) {
      int row = g * 16 + hi * 4 + r;
      M2[g][r] = fmaxf(fmaxf(pmax[row], pmax[32 + row]), fmaxf(pmax[64 + row], pmax[96 + row]));
      sm[g][r] = 0.f;
    }
  char* Pb = (char*)P;
  #pragma unroll
  for (int ct = 0; ct < 8; ++ct) {
    const int t = ct * 4 + w;
    if (t > tmax) continue;
    const int col = t * 16 + lr;
    #pragma unroll
    for (int g = 0; g < 2; ++g)
      #pragma unroll
      for (int r = 0; r < 4; ++r) {
        float pexp = __expf(acc[ct][g][r] - M2[g][r]);
        sm[g][r] += pexp;
        int row = g * 16 + hi * 4 + r;
        int byte = (row * 1024 + col * 2) ^ ((row & 7) << 4);
        *(u16*)(Pb + byte) = f2bf(pexp);
      }
  }
  #pragma unroll
  for (int o = 1; o < 16; o <<= 1)
    #pragma unroll
    for (int g = 0; g < 2; ++g)
      #pragma unroll
      for (int r = 0; r < 4; ++r) sm[g][r] += __shfl_xor(sm[g][r], o);
  if (lr == 0) {
    #pragma unroll
    for (int g = 0; g < 2; ++g)
      #pragma unroll
      for (int r = 0; r < 4; ++r) psum[w * 32 + g * 16 + hi * 4 + r] = sm[g][r];
  }
  __syncthreads();

  float rinv[2][4];
  #pragma unroll
  for (int g = 0; g < 2; ++g)
    #pragma unroll
    for (int r = 0; r < 4; ++r) {
      int row = g * 16 + hi * 4 + r;
      rinv[g][r] = 1.0f / (psum[row] + psum[32 + row] + psum[64 + row] + psum[96 + row]);
    }

  // ---- phase 3: out = P @ V (wave w owns output cols w*16..w*16+16); V shared by row-groups
  {
    const int n0 = w * 16;
    f32x4 oa0 = (f32x4){0.f, 0.f, 0.f, 0.f};
    f32x4 oa1 = (f32x4){0.f, 0.f, 0.f, 0.f};
    for (int ks = 0; ks < nks; ++ks) {
      bfx8 vf = *(const bfx8*)(vT + ((size_t)bh * DK_ + n0 + lr) * T_ + ks * 32 + lk);
      int byte0 = (lr * 1024 + (ks * 32 + lk) * 2) ^ ((lr & 7) << 4);
      int byte1 = ((16 + lr) * 1024 + (ks * 32 + lk) * 2) ^ ((lr & 7) << 4);
      bfx8 pa0 = *(const bfx8*)(Pb + byte0);
      bfx8 pa1 = *(const bfx8*)(Pb + byte1);
      oa0 = __builtin_amdgcn_mfma_f32_16x16x32_bf16(pa0, vf, oa0, 0, 0, 0);
      oa1 = __builtin_amdgcn_mfma_f32_16x16x32_bf16(pa1, vf, oa1, 0, 0, 0);
    }
    #pragma unroll
    for (int r = 0; r < 4; ++r) {
      int i = i0 + hi * 4 + r;
      ao[((size_t)b * T_ + i) * D_ + h * DK_ + n0 + lr] = f2bf(oa0[r] * rinv[0][r]);
    }
    #pragma unroll
    for (int r = 0; r < 4; ++r) {
      int i = i0 + 16 + hi * 4 + r;
      ao[((size_t)b * T_ + i) * D_ + h * DK_ + n0 + lr] = f2bf(oa1[r] * rinv[1][r]);
    }
  }
}

extern "C" void kernel_launch(void* const* d_in, const int* in_sizes, int n_in,
                              void* d_out, int out_size, void* d_ws, size_t ws_size,
                              hipStream_t stream) {
  (void)in_sizes; (void)n_in; (void)out_size; (void)ws_size;
  const float* x    = (const float*)d_in[0];
  const float* tmat = (const float*)d_in[1];
  const int*   pad  = (const int*)d_in[2];
  const float* wq = (const float*)d_in[3];  const float* bq = (const float*)d_in[4];
  const float* wk = (const float*)d_in[5];  const float* bk = (const float*)d_in[6];
  const float* wv = (const float*)d_in[7];  const float* bv = (const float*)d_in[8];
  const float* wp = (const float*)d_in[9];  const float* bp = (const float*)d_in[10];
  const float* tb1w = (const float*)d_in[11]; const float* tb1b = (const float*)d_in[12];
  const float* tb2w = (const float*)d_in[13]; const float* tb2b = (const float*)d_in[14];
  const float* fc1w = (const float*)d_in[15]; const float* fc1b = (const float*)d_in[16];
  const float* fc2w = (const float*)d_in[17]; const float* fc2b = (const float*)d_in[18];
  const float* ln1g = (const float*)d_in[19]; const float* ln1b = (const float*)d_in[20];
  const float* ln2g = (const float*)d_in[21]; const float* ln2b = (const float*)d_in[22];
  float* out = (float*)d_out;

  // ---- workspace layout (with aliasing of dead buffers onto split-K partials)
  char* p = (char*)d_ws;
  u16* wqT  = (u16*)p; p += (size_t)768 * 768 * 2;
  u16* wkT  = (u16*)p; p += (size_t)768 * 768 * 2;
  u16* wvT  = (u16*)p; p += (size_t)768 * 768 * 2;
  u16* wpT  = (u16*)p; p += (size_t)768 * 768 * 2;
  u16* fc1T = (u16*)p; p += (size_t)768 * 3072 * 2;
  u16* fc2T = (u16*)p; p += (size_t)3072 * 768 * 2;
  float* x1 = (float*)p; p += (size_t)NTOK * D_ * 4;
  u16* gbuf = (u16*)p; p += (size_t)NTOK * FF_ * 2;
  char* pool = p;   // 25165824-byte overlay pool
  u16*   hbuf  = (u16*)(pool + 0);
  u16*   qb    = (u16*)(pool + 3145728);
  u16*   kb    = (u16*)(pool + 6291456);
  u16*   vTb   = (u16*)(pool + 9437184);
  float* biasM = (float*)(pool + 12582912);
  u16*   ao    = (u16*)(pool + 16777216);
  u16*   h2    = (u16*)(pool + 19922944);
  float* partP = (float*)(pool + 0);   // proj split-2 partials (12.6 MB) — qb/kb/vTb/hbuf dead
  float* partF = (float*)(pool + 0);   // ffn2 split-4 partials (25.2 MB) — whole pool dead

  // prep: transposes + LN1 + bias MLP in one dispatch
  prep_kernel<<<13056, 256, 0, stream>>>(x, wq, wk, wv, wp, fc1w, fc2w,
                                         wqT, wkT, wvT, wpT, fc1T, fc2T,
                                         ln1g, ln1b, hbuf,
                                         tmat, pad, tb1w, tb1b, tb2w, tb2b, biasM);

  gemm_qkv<<<dim3(6, 16, 3), 256, 0, stream>>>(hbuf, wqT, wkT, wvT, bq, bk, bv, qb, kb, vTb);
  attn_kernel<<<768, 256, 0, stream>>>(qb, kb, vTb, biasM, ao);

  // proj: split-K=2 (192 blocks), then reduce fused with LN2
  gemm_part<<<dim3(6, 16, 2), 256, 0, stream>>>(ao, wpT, partP, NTOK, 768, 768, 384);
  reduce_ln<<<NTOK, 256, 0, stream>>>(partP, x, bp, ln2g, ln2b, x1, h2);

  // FFN1 (384 blocks)
  gemm_gelu<<<dim3(24, 16), 256, 0, stream>>>(h2, fc1T, fc1b, gbuf, NTOK, FF_, 768);

  // FFN2: split-K=4 (384 blocks), then reduce + residual
  gemm_part<<<dim3(6, 16, 4), 256, 0, stream>>>(gbuf, fc2T, partF, NTOK, 768, 3072, 768);
  reduce_out<<<NTOK * D_ / 4 / 256, 256, 0, stream>>>(partF, x1, fc2b, out);
}